// Round 2
// baseline (2452.296 us; speedup 1.0000x reference)
//
#include <hip/hip_runtime.h>
#include <hip/hip_bf16.h>

#define D_MODEL 1024
#define D_STATE 16
#define D_CONV 4
#define D_INNER 2048
#define DT_RANK 128
#define BATCH 2
#define SEQLEN 1024
#define XCOLS 160   // DT_RANK + 2*D_STATE

typedef __hip_bfloat16 bf16;

__device__ __forceinline__ float bf16_bits_to_f(unsigned short us) {
    unsigned int b = ((unsigned int)us) << 16;
    return __uint_as_float(b);
}

// ---- dtype detection: flag=1 -> inputs are fp32, flag=0 -> bf16 ----
__global__ void detect_dtype(const void* __restrict__ x, int* __restrict__ flag) {
    __shared__ float smax[256];
    const unsigned short* p = (const unsigned short*)x;
    int i = threadIdx.x;
    float m = 0.f;
    for (int j = i; j < 2048; j += 256) {
        float v = fabsf(bf16_bits_to_f(p[2 * j]));   // even-indexed bf16 lanes
        if (!(v == v)) v = 1e30f;                    // NaN -> huge
        m = fmaxf(m, v);
    }
    smax[i] = m;
    __syncthreads();
    for (int s = 128; s > 0; s >>= 1) {
        if (i < s) smax[i] = fmaxf(smax[i], smax[i + s]);
        __syncthreads();
    }
    if (i == 0) *flag = (smax[0] > 100.f) ? 1 : 0;
}

// ---- canonicalize any input to fp32 ----
__global__ __launch_bounds__(256)
void to_f32(const void* __restrict__ src, float* __restrict__ dst, int n,
            const int* __restrict__ flag) {
    int i = blockIdx.x * blockDim.x + threadIdx.x;
    if (i >= n) return;
    if (*flag) dst[i] = ((const float*)src)[i];
    else       dst[i] = bf16_bits_to_f(((const unsigned short*)src)[i]);
}

// Generic fp32 tiled GEMM: C[M,N] = A[M,K] @ B[K,N].
// 64x64 tile, 256 threads, 4x4 outputs/thread, K-tile 16. Bounds-guarded.
// If out/flag nonnull: store bf16 when *flag==0, fp32 when *flag==1.
__global__ __launch_bounds__(256)
void gemm_tiled(const float* __restrict__ A, const float* __restrict__ B,
                float* __restrict__ C, int M, int N, int K,
                int lda, int ldb, int ldc,
                void* __restrict__ out, const int* __restrict__ flag)
{
    __shared__ float As[64][17];
    __shared__ float Bs[16][68];
    const int tid = threadIdx.x;
    const int tx = tid & 15, ty = tid >> 4;
    const int row0 = blockIdx.y * 64;
    const int col0 = blockIdx.x * 64;
    float c[4][4] = {};
    for (int k0 = 0; k0 < K; k0 += 16) {
        {   // A tile 64x16
            int m = tid >> 2, kq = (tid & 3) * 4;
            int gm = row0 + m;
            #pragma unroll
            for (int j = 0; j < 4; ++j) {
                int gk = k0 + kq + j;
                As[m][kq + j] = (gm < M && gk < K) ? A[(size_t)gm * lda + gk] : 0.f;
            }
        }
        {   // B tile 16x64
            int kk = tid >> 4, nq = (tid & 15) * 4;
            int gk = k0 + kk;
            #pragma unroll
            for (int j = 0; j < 4; ++j) {
                int gn = col0 + nq + j;
                Bs[kk][nq + j] = (gk < K && gn < N) ? B[(size_t)gk * ldb + gn] : 0.f;
            }
        }
        __syncthreads();
        #pragma unroll
        for (int kk = 0; kk < 16; ++kk) {
            float a[4], bb[4];
            #pragma unroll
            for (int i = 0; i < 4; ++i) a[i] = As[ty * 4 + i][kk];
            #pragma unroll
            for (int j = 0; j < 4; ++j) bb[j] = Bs[kk][tx * 4 + j];
            #pragma unroll
            for (int i = 0; i < 4; ++i)
                #pragma unroll
                for (int j = 0; j < 4; ++j)
                    c[i][j] = fmaf(a[i], bb[j], c[i][j]);
        }
        __syncthreads();
    }
    const int isf32 = out ? *flag : 0;
    #pragma unroll
    for (int i = 0; i < 4; ++i) {
        int gm = row0 + ty * 4 + i;
        if (gm >= M) continue;
        #pragma unroll
        for (int j = 0; j < 4; ++j) {
            int gn = col0 + tx * 4 + j;
            if (gn >= N) continue;
            size_t off = (size_t)gm * ldc + gn;
            if (out) {
                if (isf32) ((float*)out)[off] = c[i][j];
                else       ((bf16*)out)[off] = __float2bfloat16(c[i][j]);
            } else {
                C[off] = c[i][j];
            }
        }
    }
}

// Depthwise causal conv1d (4-tap) + bias + SiLU on xz[:, :, 0:2048].
__global__ __launch_bounds__(256)
void conv_silu_kernel(const float* __restrict__ xz,
                      const float* __restrict__ conv_k,
                      const float* __restrict__ conv_b,
                      float* __restrict__ u)
{
    int idx = blockIdx.x * blockDim.x + threadIdx.x;   // 2^22
    int d = idx & (D_INNER - 1);
    int t = (idx >> 11) & (SEQLEN - 1);
    int b = idx >> 21;
    float acc = conv_b[d];
    #pragma unroll
    for (int k = 0; k < D_CONV; ++k) {
        int tt = t + k - (D_CONV - 1);
        if (tt >= 0)
            acc = fmaf(xz[((size_t)(b * SEQLEN + tt)) * (2 * D_INNER) + d],
                       conv_k[k * D_INNER + d], acc);
    }
    float s = 1.f / (1.f + __expf(-acc));
    u[idx] = acc * s;
}

// Selective scan: one lane per (b, d). h[16] in registers.
__global__ __launch_bounds__(64)
void scan_kernel(const float* __restrict__ dt_pre,   // (B*L, Di)
                 const float* __restrict__ b_dt,
                 const float* __restrict__ A_log,    // (Di, N)
                 const float* __restrict__ u,        // (B*L, Di)
                 const float* __restrict__ x_dbl,    // (B*L, 160): [dt|B|C]
                 const float* __restrict__ Dvec,
                 const float* __restrict__ xz,       // z at cols [2048,4096)
                 float* __restrict__ g)              // (B*L, Di)
{
    const int b = blockIdx.x >> 5;
    const int d = ((blockIdx.x & 31) << 6) | threadIdx.x;
    float A_row[D_STATE];
    #pragma unroll
    for (int n = 0; n < D_STATE; ++n)
        A_row[n] = -__expf(A_log[d * D_STATE + n]);
    const float Dd = Dvec[d];
    const float bdt = b_dt[d];
    float h[D_STATE] = {};
    for (int t = 0; t < SEQLEN; ++t) {
        const size_t r = (size_t)b * SEQLEN + t;
        float xv = dt_pre[r * D_INNER + d] + bdt;
        float dtv = xv > 0.f ? xv + log1pf(__expf(-xv)) : log1pf(__expf(xv));
        float uv = u[r * D_INNER + d];
        float zv = xz[r * (2 * D_INNER) + D_INNER + d];
        const float* xr = x_dbl + r * XCOLS;
        float y = 0.f;
        #pragma unroll
        for (int n = 0; n < D_STATE; ++n) {
            float Bn = xr[DT_RANK + n];
            float Cn = xr[DT_RANK + D_STATE + n];
            float a = __expf(dtv * A_row[n]);
            h[n] = fmaf(a, h[n], dtv * Bn * uv);
            y = fmaf(h[n], Cn, y);
        }
        float gy = y + uv * Dd;
        float sz = zv / (1.f + __expf(-zv));
        g[r * D_INNER + d] = gy * sz;
    }
}

extern "C" void kernel_launch(void* const* d_in, const int* in_sizes, int n_in,
                              void* d_out, int out_size, void* d_ws, size_t ws_size,
                              hipStream_t stream)
{
    const int BL = BATCH * SEQLEN;                    // 2048

    // workspace layout (floats), flag in first 64 B
    int*   flag = (int*)d_ws;
    float* ws   = (float*)d_ws + 16;
    // canonical fp32 inputs
    float* xc      = ws;                                   // 2,097,152
    float* W_in_c  = xc      + (size_t)BL * D_MODEL;       // 4,194,304
    float* convk_c = W_in_c  + (size_t)D_MODEL * 2 * D_INNER; // 8,192
    float* convb_c = convk_c + (size_t)D_CONV * D_INNER;   // 2,048
    float* Wxp_c   = convb_c + D_INNER;                    // 327,680
    float* Wdt_c   = Wxp_c   + (size_t)D_INNER * XCOLS;    // 262,144
    float* bdt_c   = Wdt_c   + (size_t)DT_RANK * D_INNER;  // 2,048
    float* Alog_c  = bdt_c   + D_INNER;                    // 32,768
    float* D_c     = Alog_c  + (size_t)D_INNER * D_STATE;  // 2,048
    float* Wout_c  = D_c     + D_INNER;                    // 2,097,152
    // intermediates
    float* xz      = Wout_c  + (size_t)D_INNER * D_MODEL;  // 8,388,608
    float* u       = xz      + (size_t)BL * 2 * D_INNER;   // 4,194,304
    float* x_dbl   = u       + (size_t)BL * D_INNER;       //   327,680
    float* dt_pre  = x_dbl   + (size_t)BL * XCOLS;         // 4,194,304
    float* g       = dt_pre  + (size_t)BL * D_INNER;       // 4,194,304

    // 0) detect input dtype (fp32 vs bf16)
    detect_dtype<<<1, 256, 0, stream>>>(d_in[0], flag);

    // 1) canonicalize all inputs to fp32
    float* dsts[10] = {xc, W_in_c, convk_c, convb_c, Wxp_c, Wdt_c, bdt_c, Alog_c, D_c, Wout_c};
    for (int i = 0; i < 10; ++i) {
        int n = in_sizes[i];
        to_f32<<<(n + 255) / 256, 256, 0, stream>>>(d_in[i], dsts[i], n, flag);
    }

    // 2) xz = x @ W_in            (2048x1024)@(1024x4096)
    gemm_tiled<<<dim3((2 * D_INNER) / 64, BL / 64), 256, 0, stream>>>(
        xc, W_in_c, xz, BL, 2 * D_INNER, D_MODEL,
        D_MODEL, 2 * D_INNER, 2 * D_INNER, nullptr, nullptr);

    // 3) u = silu(causal_conv(xz[:, :2048]) + b)
    conv_silu_kernel<<<(BL * D_INNER) / 256, 256, 0, stream>>>(xz, convk_c, convb_c, u);

    // 4) x_dbl = u @ W_xproj      (2048x2048)@(2048x160)
    gemm_tiled<<<dim3((XCOLS + 63) / 64, BL / 64), 256, 0, stream>>>(
        u, Wxp_c, x_dbl, BL, XCOLS, D_INNER,
        D_INNER, XCOLS, XCOLS, nullptr, nullptr);

    // 5) dt_pre = x_dbl[:, :128] @ W_dt   (2048x128)@(128x2048)
    gemm_tiled<<<dim3(D_INNER / 64, BL / 64), 256, 0, stream>>>(
        x_dbl, Wdt_c, dt_pre, BL, D_INNER, DT_RANK,
        XCOLS, D_INNER, D_INNER, nullptr, nullptr);

    // 6) selective scan -> g = (y + u*D) * silu(z)
    scan_kernel<<<BATCH * (D_INNER / 64), 64, 0, stream>>>(
        dt_pre, bdt_c, Alog_c, u, x_dbl, D_c, xz, g);

    // 7) out = g @ W_out          (2048x2048)@(2048x1024), dtype per flag
    gemm_tiled<<<dim3(D_MODEL / 64, BL / 64), 256, 0, stream>>>(
        g, Wout_c, nullptr, BL, D_MODEL, D_INNER,
        D_INNER, D_MODEL, D_MODEL, d_out, flag);
}

// Round 3
// 1190.169 us; speedup vs baseline: 2.0605x; 2.0605x over previous
//
#include <hip/hip_runtime.h>
#include <hip/hip_bf16.h>

#define D_MODEL 1024
#define D_STATE 16
#define D_CONV 4
#define D_INNER 2048
#define DT_RANK 128
#define BATCH 2
#define SEQLEN 1024
#define XCOLS 160     // DT_RANK + 2*D_STATE
#define NCHUNK 32
#define LCHUNK 32     // SEQLEN / NCHUNK

typedef __hip_bfloat16 bf16;

// Generic fp32 tiled GEMM: C[M,N] = A[M,K] @ B[K,N].
// 64x64 tile, 256 threads, 4x4 outputs/thread, K-tile 16. Bounds-guarded.
__global__ __launch_bounds__(256)
void gemm_tiled(const float* __restrict__ A, const float* __restrict__ B,
                float* __restrict__ C, int M, int N, int K,
                int lda, int ldb, int ldc)
{
    __shared__ float As[64][17];
    __shared__ float Bs[16][68];
    const int tid = threadIdx.x;
    const int tx = tid & 15, ty = tid >> 4;
    const int row0 = blockIdx.y * 64;
    const int col0 = blockIdx.x * 64;
    float c[4][4] = {};
    for (int k0 = 0; k0 < K; k0 += 16) {
        {   // A tile 64x16
            int m = tid >> 2, kq = (tid & 3) * 4;
            int gm = row0 + m;
            #pragma unroll
            for (int j = 0; j < 4; ++j) {
                int gk = k0 + kq + j;
                As[m][kq + j] = (gm < M && gk < K) ? A[(size_t)gm * lda + gk] : 0.f;
            }
        }
        {   // B tile 16x64
            int kk = tid >> 4, nq = (tid & 15) * 4;
            int gk = k0 + kk;
            #pragma unroll
            for (int j = 0; j < 4; ++j) {
                int gn = col0 + nq + j;
                Bs[kk][nq + j] = (gk < K && gn < N) ? B[(size_t)gk * ldb + gn] : 0.f;
            }
        }
        __syncthreads();
        #pragma unroll
        for (int kk = 0; kk < 16; ++kk) {
            float a[4], bb[4];
            #pragma unroll
            for (int i = 0; i < 4; ++i) a[i] = As[ty * 4 + i][kk];
            #pragma unroll
            for (int j = 0; j < 4; ++j) bb[j] = Bs[kk][tx * 4 + j];
            #pragma unroll
            for (int i = 0; i < 4; ++i)
                #pragma unroll
                for (int j = 0; j < 4; ++j)
                    c[i][j] = fmaf(a[i], bb[j], c[i][j]);
        }
        __syncthreads();
    }
    #pragma unroll
    for (int i = 0; i < 4; ++i) {
        int gm = row0 + ty * 4 + i;
        if (gm >= M) continue;
        #pragma unroll
        for (int j = 0; j < 4; ++j) {
            int gn = col0 + tx * 4 + j;
            if (gn < N) C[(size_t)gm * ldc + gn] = c[i][j];
        }
    }
}

// Depthwise causal conv1d (4-tap) + bias + SiLU on xz[:, :, 0:2048].
__global__ __launch_bounds__(256)
void conv_silu_kernel(const float* __restrict__ xz,
                      const float* __restrict__ conv_k,
                      const float* __restrict__ conv_b,
                      float* __restrict__ u)
{
    int idx = blockIdx.x * blockDim.x + threadIdx.x;   // 2^22
    int d = idx & (D_INNER - 1);
    int t = (idx >> 11) & (SEQLEN - 1);
    int b = idx >> 21;
    float acc = conv_b[d];
    #pragma unroll
    for (int k = 0; k < D_CONV; ++k) {
        int tt = t + k - (D_CONV - 1);
        if (tt >= 0)
            acc = fmaf(xz[((size_t)(b * SEQLEN + tt)) * (2 * D_INNER) + d],
                       conv_k[k * D_INNER + d], acc);
    }
    float s = 1.f / (1.f + __expf(-acc));
    u[idx] = acc * s;
}

__device__ __forceinline__ float softplus_f(float x) {
    return x > 0.f ? x + log1pf(__expf(-x)) : log1pf(__expf(x));
}

// Chunked scan phase 1: per (b,d,chunk) compute chunk transform
//   P[n] = prod_t a_t[n],  S[n] = local scan from h=0
// Layout of P,S,hin: [((b*NCHUNK + c)*D_STATE + n)*D_INNER + d]  (d fastest: coalesced)
__global__ __launch_bounds__(256)
void scan_phase1(const float* __restrict__ dt_pre,
                 const float* __restrict__ b_dt,
                 const float* __restrict__ A_log,
                 const float* __restrict__ u,
                 const float* __restrict__ x_dbl,
                 float* __restrict__ Pst, float* __restrict__ Sst)
{
    const int d = blockIdx.x * 256 + threadIdx.x;
    const int c = blockIdx.y;
    const int b = blockIdx.z;
    float A_row[D_STATE];
    #pragma unroll
    for (int n = 0; n < D_STATE; ++n)
        A_row[n] = -__expf(A_log[d * D_STATE + n]);
    const float bdt = b_dt[d];
    float P[D_STATE], S[D_STATE];
    #pragma unroll
    for (int n = 0; n < D_STATE; ++n) { P[n] = 1.f; S[n] = 0.f; }
    const int t0 = c * LCHUNK;
    for (int t = t0; t < t0 + LCHUNK; ++t) {
        const size_t r = (size_t)b * SEQLEN + t;
        float dtv = softplus_f(dt_pre[r * D_INNER + d] + bdt);
        float uv = u[r * D_INNER + d];
        const float4* b4 = (const float4*)(x_dbl + r * XCOLS + DT_RANK);
        float Bn[D_STATE];
        #pragma unroll
        for (int q = 0; q < 4; ++q) {
            float4 v = b4[q];
            Bn[q*4+0] = v.x; Bn[q*4+1] = v.y; Bn[q*4+2] = v.z; Bn[q*4+3] = v.w;
        }
        float du = dtv * uv;
        #pragma unroll
        for (int n = 0; n < D_STATE; ++n) {
            float a = __expf(dtv * A_row[n]);
            P[n] *= a;
            S[n] = fmaf(a, S[n], du * Bn[n]);
        }
    }
    const size_t base = ((size_t)(b * NCHUNK + c) * D_STATE) * D_INNER + d;
    #pragma unroll
    for (int n = 0; n < D_STATE; ++n) {
        Pst[base + (size_t)n * D_INNER] = P[n];
        Sst[base + (size_t)n * D_INNER] = S[n];
    }
}

// Phase 2: per (b,d,n) combine chunk transforms sequentially, record h_in per chunk.
__global__ __launch_bounds__(256)
void scan_phase2(const float* __restrict__ Pst, const float* __restrict__ Sst,
                 float* __restrict__ hin)
{
    const int d = blockIdx.x * 256 + threadIdx.x;
    const int n = blockIdx.y;
    const int b = blockIdx.z;
    float h = 0.f;
    for (int c = 0; c < NCHUNK; ++c) {
        const size_t idx = ((size_t)(b * NCHUNK + c) * D_STATE + n) * D_INNER + d;
        hin[idx] = h;
        h = fmaf(Pst[idx], h, Sst[idx]);
    }
}

// Phase 3: per (b,d,chunk) re-scan seeded with h_in; fuse y, skip, silu(z) gate.
__global__ __launch_bounds__(256)
void scan_phase3(const float* __restrict__ dt_pre,
                 const float* __restrict__ b_dt,
                 const float* __restrict__ A_log,
                 const float* __restrict__ u,
                 const float* __restrict__ x_dbl,
                 const float* __restrict__ Dvec,
                 const float* __restrict__ xz,
                 const float* __restrict__ hin,
                 float* __restrict__ g)
{
    const int d = blockIdx.x * 256 + threadIdx.x;
    const int c = blockIdx.y;
    const int b = blockIdx.z;
    float A_row[D_STATE];
    #pragma unroll
    for (int n = 0; n < D_STATE; ++n)
        A_row[n] = -__expf(A_log[d * D_STATE + n]);
    const float bdt = b_dt[d];
    const float Dd = Dvec[d];
    float h[D_STATE];
    const size_t base = ((size_t)(b * NCHUNK + c) * D_STATE) * D_INNER + d;
    #pragma unroll
    for (int n = 0; n < D_STATE; ++n) h[n] = hin[base + (size_t)n * D_INNER];
    const int t0 = c * LCHUNK;
    for (int t = t0; t < t0 + LCHUNK; ++t) {
        const size_t r = (size_t)b * SEQLEN + t;
        float dtv = softplus_f(dt_pre[r * D_INNER + d] + bdt);
        float uv = u[r * D_INNER + d];
        float zv = xz[r * (2 * D_INNER) + D_INNER + d];
        const float4* x4 = (const float4*)(x_dbl + r * XCOLS + DT_RANK);
        float Bn[D_STATE], Cn[D_STATE];
        #pragma unroll
        for (int q = 0; q < 4; ++q) {
            float4 v = x4[q];
            Bn[q*4+0] = v.x; Bn[q*4+1] = v.y; Bn[q*4+2] = v.z; Bn[q*4+3] = v.w;
            float4 w = x4[q + 4];
            Cn[q*4+0] = w.x; Cn[q*4+1] = w.y; Cn[q*4+2] = w.z; Cn[q*4+3] = w.w;
        }
        float du = dtv * uv;
        float y = 0.f;
        #pragma unroll
        for (int n = 0; n < D_STATE; ++n) {
            float a = __expf(dtv * A_row[n]);
            h[n] = fmaf(a, h[n], du * Bn[n]);
            y = fmaf(h[n], Cn[n], y);
        }
        float gy = y + uv * Dd;
        float sz = zv / (1.f + __expf(-zv));
        g[r * D_INNER + d] = gy * sz;
    }
}

extern "C" void kernel_launch(void* const* d_in, const int* in_sizes, int n_in,
                              void* d_out, int out_size, void* d_ws, size_t ws_size,
                              hipStream_t stream)
{
    const float* x      = (const float*)d_in[0];
    const float* W_in   = (const float*)d_in[1];
    const float* conv_k = (const float*)d_in[2];
    const float* conv_b = (const float*)d_in[3];
    const float* W_xproj= (const float*)d_in[4];
    const float* W_dt   = (const float*)d_in[5];
    const float* b_dt   = (const float*)d_in[6];
    const float* A_log  = (const float*)d_in[7];
    const float* Dvec   = (const float*)d_in[8];
    const float* W_out  = (const float*)d_in[9];
    float* out = (float*)d_out;

    const int BL = BATCH * SEQLEN;                    // 2048
    float* ws     = (float*)d_ws;
    float* xz     = ws;                               // 8,388,608
    float* u      = xz     + (size_t)BL * 2 * D_INNER;
    float* x_dbl  = u      + (size_t)BL * D_INNER;    // 327,680
    float* dt_pre = x_dbl  + (size_t)BL * XCOLS;
    float* g      = dt_pre + (size_t)BL * D_INNER;
    float* Pst    = g      + (size_t)BL * D_INNER;    // 2,097,152
    float* Sst    = Pst    + (size_t)BATCH * NCHUNK * D_STATE * D_INNER;
    float* hin    = Sst    + (size_t)BATCH * NCHUNK * D_STATE * D_INNER;

    // 1) xz = x @ W_in            (2048x1024)@(1024x4096)
    gemm_tiled<<<dim3((2 * D_INNER) / 64, BL / 64), 256, 0, stream>>>(
        x, W_in, xz, BL, 2 * D_INNER, D_MODEL, D_MODEL, 2 * D_INNER, 2 * D_INNER);

    // 2) u = silu(causal_conv(xz[:, :2048]) + b)
    conv_silu_kernel<<<(BL * D_INNER) / 256, 256, 0, stream>>>(xz, conv_k, conv_b, u);

    // 3) x_dbl = u @ W_xproj      (2048x2048)@(2048x160)
    gemm_tiled<<<dim3((XCOLS + 63) / 64, BL / 64), 256, 0, stream>>>(
        u, W_xproj, x_dbl, BL, XCOLS, D_INNER, D_INNER, XCOLS, XCOLS);

    // 4) dt_pre = x_dbl[:, :128] @ W_dt   (2048x128)@(128x2048)
    gemm_tiled<<<dim3(D_INNER / 64, BL / 64), 256, 0, stream>>>(
        x_dbl, W_dt, dt_pre, BL, D_INNER, DT_RANK, XCOLS, D_INNER, D_INNER);

    // 5) chunked selective scan -> g = (y + u*D) * silu(z)
    scan_phase1<<<dim3(D_INNER / 256, NCHUNK, BATCH), 256, 0, stream>>>(
        dt_pre, b_dt, A_log, u, x_dbl, Pst, Sst);
    scan_phase2<<<dim3(D_INNER / 256, D_STATE, BATCH), 256, 0, stream>>>(
        Pst, Sst, hin);
    scan_phase3<<<dim3(D_INNER / 256, NCHUNK, BATCH), 256, 0, stream>>>(
        dt_pre, b_dt, A_log, u, x_dbl, Dvec, xz, hin, g);

    // 6) out = g @ W_out          (2048x2048)@(2048x1024)
    gemm_tiled<<<dim3(D_MODEL / 64, BL / 64), 256, 0, stream>>>(
        g, W_out, out, BL, D_MODEL, D_INNER, D_INNER, D_MODEL, D_MODEL);
}

// Round 4
// 365.005 us; speedup vs baseline: 6.7185x; 3.2607x over previous
//
#include <hip/hip_runtime.h>
#include <hip/hip_bf16.h>

#define D_MODEL 1024
#define D_STATE 16
#define D_CONV 4
#define D_INNER 2048
#define DT_RANK 128
#define BATCH 2
#define SEQLEN 1024
#define XCOLS 160     // DT_RANK + 2*D_STATE
#define NCHUNK 32
#define LCHUNK 32     // SEQLEN / NCHUNK

typedef __hip_bfloat16 bf16;
typedef __attribute__((ext_vector_type(8))) short short8;
typedef __attribute__((ext_vector_type(4))) float f32x4;

// ---------------- converts ----------------

__global__ __launch_bounds__(256)
void convert_f32_bf16(const float* __restrict__ src, bf16* __restrict__ dst, int n)
{
    int i = blockIdx.x * 256 + threadIdx.x;
    if (i < n) dst[i] = __float2bfloat16(src[i]);
}

// x_dbl[:, 0:128] -> contiguous bf16 (2048 x 128)
__global__ __launch_bounds__(256)
void convert_dtlow(const float* __restrict__ x_dbl, bf16* __restrict__ dst)
{
    int i = blockIdx.x * 256 + threadIdx.x;   // 262144
    int row = i >> 7, col = i & 127;
    dst[i] = __float2bfloat16(x_dbl[(size_t)row * XCOLS + col]);
}

// B[K][N] fp32 row-major -> Bt[Npad][K] bf16 row-major (zero-fill n >= N).
// Grid: (Npad/32, K/32), 256 threads (32x8).
__global__ __launch_bounds__(256)
void transpose_f32_bf16(const float* __restrict__ B, bf16* __restrict__ Bt,
                        int K, int N)
{
    __shared__ float t[32][33];
    const int tx = threadIdx.x & 31, ty = threadIdx.x >> 5;
    const int n0 = blockIdx.x * 32, k0 = blockIdx.y * 32;
    #pragma unroll
    for (int r = 0; r < 4; ++r) {
        int k = k0 + ty + r * 8;
        int n = n0 + tx;
        t[ty + r * 8][tx] = (n < N) ? B[(size_t)k * N + n] : 0.f;
    }
    __syncthreads();
    #pragma unroll
    for (int r = 0; r < 4; ++r) {
        int n = n0 + ty + r * 8;
        int k = k0 + tx;
        Bt[(size_t)n * K + k] = __float2bfloat16(t[tx][ty + r * 8]);
    }
}

// ---------------- MFMA GEMM ----------------
// C[M,N] = A[M,K](bf16,row-major) @ Bt[Npad,K](bf16,row-major == B^T), fp32 out.
// 128x128 tile, BK=32, 256 threads (4 waves), wave = 64x64 via 4x4 of 16x16x32.
// M, K multiples of 128/32; N guarded on store; Bt padded to gridDim.x*128 rows.
__global__ __launch_bounds__(256)
void gemm_mfma_bt(const bf16* __restrict__ A, const bf16* __restrict__ Bt,
                  float* __restrict__ C, int M, int N, int K, int ldc)
{
    __shared__ short As[128 * 32];
    __shared__ short Bs[128 * 32];
    const int tid = threadIdx.x;
    const int lane = tid & 63, wave = tid >> 6;
    const int wm = (wave >> 1) * 64, wn = (wave & 1) * 64;
    const int row0 = blockIdx.y * 128, col0 = blockIdx.x * 128;
    const int r_m = lane & 15, r_q = lane >> 4;

    // staging: thread t -> rows srow, srow+64; 16B chunk schk
    const int srow = tid >> 2, schk = (tid & 3) * 8;
    const uint4* Ag0 = (const uint4*)(A  + (size_t)(row0 + srow)      * K + schk);
    const uint4* Ag1 = (const uint4*)(A  + (size_t)(row0 + srow + 64) * K + schk);
    const uint4* Bg0 = (const uint4*)(Bt + (size_t)(col0 + srow)      * K + schk);
    const uint4* Bg1 = (const uint4*)(Bt + (size_t)(col0 + srow + 64) * K + schk);
    uint4* AsW0 = (uint4*)&As[srow * 32 + schk];
    uint4* AsW1 = (uint4*)&As[(srow + 64) * 32 + schk];
    uint4* BsW0 = (uint4*)&Bs[srow * 32 + schk];
    uint4* BsW1 = (uint4*)&Bs[(srow + 64) * 32 + schk];

    f32x4 acc[4][4];
    #pragma unroll
    for (int i = 0; i < 4; ++i)
        #pragma unroll
        for (int j = 0; j < 4; ++j)
            #pragma unroll
            for (int r = 0; r < 4; ++r) acc[i][j][r] = 0.f;

    for (int k0 = 0; k0 < K; k0 += 32) {
        const int kq = k0 >> 3;                 // uint4 index step
        uint4 a0 = Ag0[kq], a1 = Ag1[kq], b0 = Bg0[kq], b1 = Bg1[kq];
        __syncthreads();                        // prev-iter LDS reads done
        *AsW0 = a0; *AsW1 = a1; *BsW0 = b0; *BsW1 = b1;
        __syncthreads();                        // staging visible
        short8 af[4], bf[4];
        #pragma unroll
        for (int i = 0; i < 4; ++i)
            af[i] = *(const short8*)&As[(wm + i * 16 + r_m) * 32 + r_q * 8];
        #pragma unroll
        for (int j = 0; j < 4; ++j)
            bf[j] = *(const short8*)&Bs[(wn + j * 16 + r_m) * 32 + r_q * 8];
        #pragma unroll
        for (int i = 0; i < 4; ++i)
            #pragma unroll
            for (int j = 0; j < 4; ++j)
                acc[i][j] = __builtin_amdgcn_mfma_f32_16x16x32_bf16(
                    af[i], bf[j], acc[i][j], 0, 0, 0);
    }

    #pragma unroll
    for (int i = 0; i < 4; ++i) {
        #pragma unroll
        for (int j = 0; j < 4; ++j) {
            int row = row0 + wm + i * 16 + r_q * 4;
            int col = col0 + wn + j * 16 + r_m;
            if (col < N) {
                #pragma unroll
                for (int r = 0; r < 4; ++r)
                    C[(size_t)(row + r) * ldc + col] = acc[i][j][r];
            }
        }
    }
}

// ---------------- conv + silu ----------------
__global__ __launch_bounds__(256)
void conv_silu_kernel(const float* __restrict__ xz,
                      const float* __restrict__ conv_k,
                      const float* __restrict__ conv_b,
                      float* __restrict__ u, bf16* __restrict__ u_bf)
{
    int idx = blockIdx.x * blockDim.x + threadIdx.x;   // 2^22
    int d = idx & (D_INNER - 1);
    int t = (idx >> 11) & (SEQLEN - 1);
    int b = idx >> 21;
    float acc = conv_b[d];
    #pragma unroll
    for (int k = 0; k < D_CONV; ++k) {
        int tt = t + k - (D_CONV - 1);
        if (tt >= 0)
            acc = fmaf(xz[((size_t)(b * SEQLEN + tt)) * (2 * D_INNER) + d],
                       conv_k[k * D_INNER + d], acc);
    }
    float s = 1.f / (1.f + __expf(-acc));
    float uv = acc * s;
    u[idx] = uv;
    u_bf[idx] = __float2bfloat16(uv);
}

__device__ __forceinline__ float softplus_f(float x) {
    return x > 0.f ? x + log1pf(__expf(-x)) : log1pf(__expf(x));
}

// ---------------- chunked scan ----------------
__global__ __launch_bounds__(256)
void scan_phase1(const float* __restrict__ dt_pre,
                 const float* __restrict__ b_dt,
                 const float* __restrict__ A_log,
                 const float* __restrict__ u,
                 const float* __restrict__ x_dbl,
                 float* __restrict__ Pst, float* __restrict__ Sst)
{
    const int d = blockIdx.x * 256 + threadIdx.x;
    const int c = blockIdx.y;
    const int b = blockIdx.z;
    float A_row[D_STATE];
    #pragma unroll
    for (int n = 0; n < D_STATE; ++n)
        A_row[n] = -__expf(A_log[d * D_STATE + n]);
    const float bdt = b_dt[d];
    float P[D_STATE], S[D_STATE];
    #pragma unroll
    for (int n = 0; n < D_STATE; ++n) { P[n] = 1.f; S[n] = 0.f; }
    const int t0 = c * LCHUNK;
    for (int t = t0; t < t0 + LCHUNK; ++t) {
        const size_t r = (size_t)b * SEQLEN + t;
        float dtv = softplus_f(dt_pre[r * D_INNER + d] + bdt);
        float uv = u[r * D_INNER + d];
        const float4* b4 = (const float4*)(x_dbl + r * XCOLS + DT_RANK);
        float Bn[D_STATE];
        #pragma unroll
        for (int q = 0; q < 4; ++q) {
            float4 v = b4[q];
            Bn[q*4+0] = v.x; Bn[q*4+1] = v.y; Bn[q*4+2] = v.z; Bn[q*4+3] = v.w;
        }
        float du = dtv * uv;
        #pragma unroll
        for (int n = 0; n < D_STATE; ++n) {
            float a = __expf(dtv * A_row[n]);
            P[n] *= a;
            S[n] = fmaf(a, S[n], du * Bn[n]);
        }
    }
    const size_t base = ((size_t)(b * NCHUNK + c) * D_STATE) * D_INNER + d;
    #pragma unroll
    for (int n = 0; n < D_STATE; ++n) {
        Pst[base + (size_t)n * D_INNER] = P[n];
        Sst[base + (size_t)n * D_INNER] = S[n];
    }
}

__global__ __launch_bounds__(256)
void scan_phase2(const float* __restrict__ Pst, const float* __restrict__ Sst,
                 float* __restrict__ hin)
{
    const int d = blockIdx.x * 256 + threadIdx.x;
    const int n = blockIdx.y;
    const int b = blockIdx.z;
    float h = 0.f;
    for (int c = 0; c < NCHUNK; ++c) {
        const size_t idx = ((size_t)(b * NCHUNK + c) * D_STATE + n) * D_INNER + d;
        hin[idx] = h;
        h = fmaf(Pst[idx], h, Sst[idx]);
    }
}

__global__ __launch_bounds__(256)
void scan_phase3(const float* __restrict__ dt_pre,
                 const float* __restrict__ b_dt,
                 const float* __restrict__ A_log,
                 const float* __restrict__ u,
                 const float* __restrict__ x_dbl,
                 const float* __restrict__ Dvec,
                 const float* __restrict__ xz,
                 const float* __restrict__ hin,
                 bf16* __restrict__ g_bf)
{
    const int d = blockIdx.x * 256 + threadIdx.x;
    const int c = blockIdx.y;
    const int b = blockIdx.z;
    float A_row[D_STATE];
    #pragma unroll
    for (int n = 0; n < D_STATE; ++n)
        A_row[n] = -__expf(A_log[d * D_STATE + n]);
    const float bdt = b_dt[d];
    const float Dd = Dvec[d];
    float h[D_STATE];
    const size_t base = ((size_t)(b * NCHUNK + c) * D_STATE) * D_INNER + d;
    #pragma unroll
    for (int n = 0; n < D_STATE; ++n) h[n] = hin[base + (size_t)n * D_INNER];
    const int t0 = c * LCHUNK;
    for (int t = t0; t < t0 + LCHUNK; ++t) {
        const size_t r = (size_t)b * SEQLEN + t;
        float dtv = softplus_f(dt_pre[r * D_INNER + d] + bdt);
        float uv = u[r * D_INNER + d];
        float zv = xz[r * (2 * D_INNER) + D_INNER + d];
        const float4* x4 = (const float4*)(x_dbl + r * XCOLS + DT_RANK);
        float Bn[D_STATE], Cn[D_STATE];
        #pragma unroll
        for (int q = 0; q < 4; ++q) {
            float4 v = x4[q];
            Bn[q*4+0] = v.x; Bn[q*4+1] = v.y; Bn[q*4+2] = v.z; Bn[q*4+3] = v.w;
            float4 w = x4[q + 4];
            Cn[q*4+0] = w.x; Cn[q*4+1] = w.y; Cn[q*4+2] = w.z; Cn[q*4+3] = w.w;
        }
        float du = dtv * uv;
        float y = 0.f;
        #pragma unroll
        for (int n = 0; n < D_STATE; ++n) {
            float a = __expf(dtv * A_row[n]);
            h[n] = fmaf(a, h[n], du * Bn[n]);
            y = fmaf(h[n], Cn[n], y);
        }
        float gy = y + uv * Dd;
        float sz = zv / (1.f + __expf(-zv));
        g_bf[r * D_INNER + d] = __float2bfloat16(gy * sz);
    }
}

extern "C" void kernel_launch(void* const* d_in, const int* in_sizes, int n_in,
                              void* d_out, int out_size, void* d_ws, size_t ws_size,
                              hipStream_t stream)
{
    const float* x      = (const float*)d_in[0];
    const float* W_in   = (const float*)d_in[1];
    const float* conv_k = (const float*)d_in[2];
    const float* conv_b = (const float*)d_in[3];
    const float* W_xproj= (const float*)d_in[4];
    const float* W_dt   = (const float*)d_in[5];
    const float* b_dt   = (const float*)d_in[6];
    const float* A_log  = (const float*)d_in[7];
    const float* Dvec   = (const float*)d_in[8];
    const float* W_out  = (const float*)d_in[9];
    float* out = (float*)d_out;

    const int BL = BATCH * SEQLEN;                    // 2048

    // fp32 intermediates
    float* ws     = (float*)d_ws;
    float* xz     = ws;                                // 8,388,608
    float* u      = xz     + (size_t)BL * 2 * D_INNER; // 4,194,304
    float* x_dbl  = u      + (size_t)BL * D_INNER;     //   327,680
    float* dt_pre = x_dbl  + (size_t)BL * XCOLS;       // 4,194,304
    float* Pst    = dt_pre + (size_t)BL * D_INNER;     // 2,097,152
    float* Sst    = Pst    + (size_t)BATCH * NCHUNK * D_STATE * D_INNER;
    float* hin    = Sst    + (size_t)BATCH * NCHUNK * D_STATE * D_INNER;
    // bf16 buffers
    bf16* x_bf   = (bf16*)(hin + (size_t)BATCH * NCHUNK * D_STATE * D_INNER);
    bf16* Win_t  = x_bf  + (size_t)BL * D_MODEL;          // 4096 x 1024
    bf16* u_bf   = Win_t + (size_t)4096 * 1024;           // 2048 x 2048
    bf16* Wxp_t  = u_bf  + (size_t)BL * D_INNER;          // 256  x 2048 (padded)
    bf16* dtA_bf = Wxp_t + (size_t)256 * 2048;            // 2048 x 128
    bf16* Wdt_t  = dtA_bf+ (size_t)BL * DT_RANK;          // 2048 x 128
    bf16* g_bf   = Wdt_t + (size_t)2048 * 128;            // 2048 x 2048
    bf16* Wout_t = g_bf  + (size_t)BL * D_INNER;          // 1024 x 2048

    // 0) converts / transposes (must run every call; no persistence allowed)
    convert_f32_bf16<<<(BL * D_MODEL) / 256, 256, 0, stream>>>(x, x_bf, BL * D_MODEL);
    transpose_f32_bf16<<<dim3(4096 / 32, 1024 / 32), 256, 0, stream>>>(W_in, Win_t, D_MODEL, 2 * D_INNER);
    transpose_f32_bf16<<<dim3(256 / 32, 2048 / 32), 256, 0, stream>>>(W_xproj, Wxp_t, D_INNER, XCOLS);
    transpose_f32_bf16<<<dim3(2048 / 32, 128 / 32), 256, 0, stream>>>(W_dt, Wdt_t, DT_RANK, D_INNER);
    transpose_f32_bf16<<<dim3(1024 / 32, 2048 / 32), 256, 0, stream>>>(W_out, Wout_t, D_INNER, D_MODEL);

    // 1) xz = x @ W_in            (2048x1024)@(1024x4096)
    gemm_mfma_bt<<<dim3(4096 / 128, BL / 128), 256, 0, stream>>>(
        x_bf, Win_t, xz, BL, 2 * D_INNER, D_MODEL, 2 * D_INNER);

    // 2) u = silu(causal_conv(xz[:, :2048]) + b)  (+ bf16 mirror)
    conv_silu_kernel<<<(BL * D_INNER) / 256, 256, 0, stream>>>(xz, conv_k, conv_b, u, u_bf);

    // 3) x_dbl = u @ W_xproj      (2048x2048)@(2048x160), N padded to 256
    gemm_mfma_bt<<<dim3(256 / 128, BL / 128), 256, 0, stream>>>(
        u_bf, Wxp_t, x_dbl, BL, XCOLS, D_INNER, XCOLS);

    // 4) dt_pre = x_dbl[:, :128] @ W_dt   (2048x128)@(128x2048)
    convert_dtlow<<<(BL * DT_RANK) / 256, 256, 0, stream>>>(x_dbl, dtA_bf);
    gemm_mfma_bt<<<dim3(2048 / 128, BL / 128), 256, 0, stream>>>(
        dtA_bf, Wdt_t, dt_pre, BL, D_INNER, DT_RANK, D_INNER);

    // 5) chunked selective scan -> g_bf = bf16((y + u*D) * silu(z))
    scan_phase1<<<dim3(D_INNER / 256, NCHUNK, BATCH), 256, 0, stream>>>(
        dt_pre, b_dt, A_log, u, x_dbl, Pst, Sst);
    scan_phase2<<<dim3(D_INNER / 256, D_STATE, BATCH), 256, 0, stream>>>(
        Pst, Sst, hin);
    scan_phase3<<<dim3(D_INNER / 256, NCHUNK, BATCH), 256, 0, stream>>>(
        dt_pre, b_dt, A_log, u, x_dbl, Dvec, xz, hin, g_bf);

    // 6) out = g @ W_out          (2048x2048)@(2048x1024)
    gemm_mfma_bt<<<dim3(1024 / 128, BL / 128), 256, 0, stream>>>(
        g_bf, Wout_t, out, BL, D_MODEL, D_INNER, D_MODEL);
}

// Round 5
// 259.907 us; speedup vs baseline: 9.4353x; 1.4044x over previous
//
#include <hip/hip_runtime.h>
#include <hip/hip_bf16.h>

#define D_MODEL 1024
#define D_STATE 16
#define D_CONV 4
#define D_INNER 2048
#define DT_RANK 128
#define BATCH 2
#define SEQLEN 1024
#define XCOLS 160     // DT_RANK + 2*D_STATE
#define NCHUNK 64
#define LCHUNK 16     // SEQLEN / NCHUNK

typedef __hip_bfloat16 bf16;
typedef __attribute__((ext_vector_type(8))) short short8;
typedef __attribute__((ext_vector_type(4))) float f32x4;

__device__ __forceinline__ unsigned short f2bf_bits(float f) {
    bf16 h = __float2bfloat16(f);
    return *(unsigned short*)&h;
}

// ---------------- converts ----------------

__global__ __launch_bounds__(256)
void convert_f32_bf16(const float* __restrict__ src, bf16* __restrict__ dst, int n)
{
    int i = blockIdx.x * 256 + threadIdx.x;
    if (i < n) dst[i] = __float2bfloat16(src[i]);
}

// B[K][N] fp32 row-major -> Bt[Npad][K] bf16 row-major (zero-fill n >= N).
__global__ __launch_bounds__(256)
void transpose_f32_bf16(const float* __restrict__ B, bf16* __restrict__ Bt,
                        int K, int N)
{
    __shared__ float t[32][33];
    const int tx = threadIdx.x & 31, ty = threadIdx.x >> 5;
    const int n0 = blockIdx.x * 32, k0 = blockIdx.y * 32;
    #pragma unroll
    for (int r = 0; r < 4; ++r) {
        int k = k0 + ty + r * 8;
        int n = n0 + tx;
        t[ty + r * 8][tx] = (n < N) ? B[(size_t)k * N + n] : 0.f;
    }
    __syncthreads();
    #pragma unroll
    for (int r = 0; r < 4; ++r) {
        int n = n0 + ty + r * 8;
        int k = k0 + tx;
        Bt[(size_t)n * K + k] = __float2bfloat16(t[tx][ty + r * 8]);
    }
}

// ---------------- MFMA GEMM (split-K capable) ----------------
// C_z[M,ldc] = A[M,K-chunk] @ Bt[Npad,K-chunk]^T, chunk z = blockIdx.z.
// 128x128 tile, BK=32, 256 threads (4 waves), wave = 64x64 via 4x4 of 16x16x32.
__global__ __launch_bounds__(256)
void gemm_mfma_bt(const bf16* __restrict__ A, const bf16* __restrict__ Bt,
                  float* __restrict__ C, int M, int N, int K, int ldc, int kchunk)
{
    __shared__ short As[128 * 32];
    __shared__ short Bs[128 * 32];
    const int tid = threadIdx.x;
    const int lane = tid & 63, wave = tid >> 6;
    const int wm = (wave >> 1) * 64, wn = (wave & 1) * 64;
    const int row0 = blockIdx.y * 128, col0 = blockIdx.x * 128;
    const int r_m = lane & 15, r_q = lane >> 4;
    const int kstart = blockIdx.z * kchunk;
    float* Cz = C + (size_t)blockIdx.z * M * ldc;

    const int srow = tid >> 2, schk = (tid & 3) * 8;
    const uint4* Ag0 = (const uint4*)(A  + (size_t)(row0 + srow)      * K + kstart + schk);
    const uint4* Ag1 = (const uint4*)(A  + (size_t)(row0 + srow + 64) * K + kstart + schk);
    const uint4* Bg0 = (const uint4*)(Bt + (size_t)(col0 + srow)      * K + kstart + schk);
    const uint4* Bg1 = (const uint4*)(Bt + (size_t)(col0 + srow + 64) * K + kstart + schk);
    uint4* AsW0 = (uint4*)&As[srow * 32 + schk];
    uint4* AsW1 = (uint4*)&As[(srow + 64) * 32 + schk];
    uint4* BsW0 = (uint4*)&Bs[srow * 32 + schk];
    uint4* BsW1 = (uint4*)&Bs[(srow + 64) * 32 + schk];

    f32x4 acc[4][4];
    #pragma unroll
    for (int i = 0; i < 4; ++i)
        #pragma unroll
        for (int j = 0; j < 4; ++j)
            #pragma unroll
            for (int r = 0; r < 4; ++r) acc[i][j][r] = 0.f;

    for (int k0 = 0; k0 < kchunk; k0 += 32) {
        const int kq = k0 >> 3;
        uint4 a0 = Ag0[kq], a1 = Ag1[kq], b0 = Bg0[kq], b1 = Bg1[kq];
        __syncthreads();
        *AsW0 = a0; *AsW1 = a1; *BsW0 = b0; *BsW1 = b1;
        __syncthreads();
        short8 af[4], bfr[4];
        #pragma unroll
        for (int i = 0; i < 4; ++i)
            af[i] = *(const short8*)&As[(wm + i * 16 + r_m) * 32 + r_q * 8];
        #pragma unroll
        for (int j = 0; j < 4; ++j)
            bfr[j] = *(const short8*)&Bs[(wn + j * 16 + r_m) * 32 + r_q * 8];
        #pragma unroll
        for (int i = 0; i < 4; ++i)
            #pragma unroll
            for (int j = 0; j < 4; ++j)
                acc[i][j] = __builtin_amdgcn_mfma_f32_16x16x32_bf16(
                    af[i], bfr[j], acc[i][j], 0, 0, 0);
    }

    #pragma unroll
    for (int i = 0; i < 4; ++i) {
        #pragma unroll
        for (int j = 0; j < 4; ++j) {
            int row = row0 + wm + i * 16 + r_q * 4;
            int col = col0 + wn + j * 16 + r_m;
            if (col < N) {
                #pragma unroll
                for (int r = 0; r < 4; ++r)
                    Cz[(size_t)(row + r) * ldc + col] = acc[i][j][r];
            }
        }
    }
}

// reduce 8 split-K partials (ldc=256) -> x_dbl fp32 (160 cols) + dt_low bf16 (128 cols)
__global__ __launch_bounds__(256)
void reduce_xdbl(const float* __restrict__ Cpart, float* __restrict__ x_dbl,
                 bf16* __restrict__ dtA_bf)
{
    int i = blockIdx.x * 256 + threadIdx.x;          // 2048*160
    if (i >= 2048 * XCOLS) return;
    int r = i / XCOLS, c = i - r * XCOLS;
    float s = 0.f;
    #pragma unroll
    for (int z = 0; z < 8; ++z)
        s += Cpart[(size_t)z * 2048 * 256 + (size_t)r * 256 + c];
    x_dbl[i] = s;
    if (c < DT_RANK) dtA_bf[(size_t)r * DT_RANK + c] = __float2bfloat16(s);
}

// reduce 2 split-K partials -> out fp32, float4
__global__ __launch_bounds__(256)
void reduce_out(const float* __restrict__ Cpart, float* __restrict__ out)
{
    int i = blockIdx.x * 256 + threadIdx.x;          // (2048*1024)/4
    const float4* p0 = (const float4*)Cpart;
    const float4* p1 = p0 + (size_t)2048 * 1024 / 4;
    float4 a = p0[i], b = p1[i];
    float4 r; r.x = a.x + b.x; r.y = a.y + b.y; r.z = a.z + b.z; r.w = a.w + b.w;
    ((float4*)out)[i] = r;
}

// ---------------- conv + silu (float4 over d) ----------------
__global__ __launch_bounds__(256)
void conv_silu_kernel(const float* __restrict__ xz,
                      const float* __restrict__ conv_k,
                      const float* __restrict__ conv_b,
                      float* __restrict__ u, bf16* __restrict__ u_bf)
{
    int idx4 = blockIdx.x * 256 + threadIdx.x;       // B*L*Di/4 = 1048576
    int d4 = idx4 & (D_INNER / 4 - 1);
    int t = (idx4 >> 9) & (SEQLEN - 1);
    int b = idx4 >> 19;
    float4 acc = ((const float4*)conv_b)[d4];
    #pragma unroll
    for (int k = 0; k < D_CONV; ++k) {
        int tt = t + k - (D_CONV - 1);
        if (tt >= 0) {
            float4 xv = ((const float4*)xz)[(size_t)(b * SEQLEN + tt) * (2 * D_INNER / 4) + d4];
            float4 kv = ((const float4*)conv_k)[k * (D_INNER / 4) + d4];
            acc.x = fmaf(xv.x, kv.x, acc.x);
            acc.y = fmaf(xv.y, kv.y, acc.y);
            acc.z = fmaf(xv.z, kv.z, acc.z);
            acc.w = fmaf(xv.w, kv.w, acc.w);
        }
    }
    float4 uv;
    uv.x = acc.x / (1.f + __expf(-acc.x));
    uv.y = acc.y / (1.f + __expf(-acc.y));
    uv.z = acc.z / (1.f + __expf(-acc.z));
    uv.w = acc.w / (1.f + __expf(-acc.w));
    ((float4*)u)[idx4] = uv;
    ushort4 pk;
    pk.x = f2bf_bits(uv.x); pk.y = f2bf_bits(uv.y);
    pk.z = f2bf_bits(uv.z); pk.w = f2bf_bits(uv.w);
    ((ushort4*)u_bf)[idx4] = pk;
}

__device__ __forceinline__ float softplus_f(float x) {
    return fmaxf(x, 0.f) + __logf(1.f + __expf(-fabsf(x)));
}

// ---------------- chunked scan ----------------
__global__ __launch_bounds__(256)
void scan_phase1(const float* __restrict__ dt_pre,
                 const float* __restrict__ b_dt,
                 const float* __restrict__ A_log,
                 const float* __restrict__ u,
                 const float* __restrict__ x_dbl,
                 float* __restrict__ Pst, float* __restrict__ Sst)
{
    __shared__ float Bsm[LCHUNK][16];
    const int d = blockIdx.x * 256 + threadIdx.x;
    const int c = blockIdx.y, b = blockIdx.z;
    const int t0 = c * LCHUNK;
    {   // stage B rows (shared by all d in block)
        int tt = threadIdx.x >> 4, n = threadIdx.x & 15;
        Bsm[tt][n] = x_dbl[(size_t)(b * SEQLEN + t0 + tt) * XCOLS + DT_RANK + n];
    }
    float A_row[D_STATE];
    #pragma unroll
    for (int n = 0; n < D_STATE; ++n)
        A_row[n] = -__expf(A_log[d * D_STATE + n]);
    const float bdt = b_dt[d];
    __syncthreads();
    float P[D_STATE], S[D_STATE];
    #pragma unroll
    for (int n = 0; n < D_STATE; ++n) { P[n] = 1.f; S[n] = 0.f; }
    const float* dpp = dt_pre + (size_t)(b * SEQLEN + t0) * D_INNER + d;
    const float* upp = u + (size_t)(b * SEQLEN + t0) * D_INNER + d;
    #pragma unroll
    for (int t = 0; t < LCHUNK; ++t) {
        float xv = dpp[(size_t)t * D_INNER] + bdt;
        float dtv = softplus_f(xv);
        float du = dtv * upp[(size_t)t * D_INNER];
        const float4* b4 = (const float4*)&Bsm[t][0];
        #pragma unroll
        for (int q = 0; q < 4; ++q) {
            float4 v = b4[q];
            float Bn[4] = {v.x, v.y, v.z, v.w};
            #pragma unroll
            for (int e = 0; e < 4; ++e) {
                int n = q * 4 + e;
                float a = __expf(dtv * A_row[n]);
                P[n] *= a;
                S[n] = fmaf(a, S[n], du * Bn[e]);
            }
        }
    }
    const size_t base = ((size_t)(b * NCHUNK + c) * D_STATE) * D_INNER + d;
    #pragma unroll
    for (int n = 0; n < D_STATE; ++n) {
        Pst[base + (size_t)n * D_INNER] = P[n];
        Sst[base + (size_t)n * D_INNER] = S[n];
    }
}

// Phase 2: combine chunk transforms; write h_in per chunk IN-PLACE over Sst.
__global__ __launch_bounds__(256)
void scan_phase2(const float* __restrict__ Pst, float* __restrict__ Sst)
{
    const int d = blockIdx.x * 256 + threadIdx.x;
    const int n = blockIdx.y;
    const int b = blockIdx.z;
    float h = 0.f;
    for (int c = 0; c < NCHUNK; ++c) {
        const size_t idx = ((size_t)(b * NCHUNK + c) * D_STATE + n) * D_INNER + d;
        float Pv = Pst[idx], Sv = Sst[idx];
        Sst[idx] = h;                       // h_in for chunk c
        h = fmaf(Pv, h, Sv);
    }
}

__global__ __launch_bounds__(256)
void scan_phase3(const float* __restrict__ dt_pre,
                 const float* __restrict__ b_dt,
                 const float* __restrict__ A_log,
                 const float* __restrict__ u,
                 const float* __restrict__ x_dbl,
                 const float* __restrict__ Dvec,
                 const float* __restrict__ xz,
                 const float* __restrict__ hin,   // == Sst after phase2
                 bf16* __restrict__ g_bf)
{
    __shared__ float BCs[LCHUNK][32];
    const int d = blockIdx.x * 256 + threadIdx.x;
    const int c = blockIdx.y, b = blockIdx.z;
    const int t0 = c * LCHUNK;
    {   // stage B and C rows
        int i0 = threadIdx.x;
        int tt = i0 >> 5, col = i0 & 31;
        BCs[tt][col] = x_dbl[(size_t)(b * SEQLEN + t0 + tt) * XCOLS + DT_RANK + col];
        int i1 = i0 + 256;
        tt = i1 >> 5; col = i1 & 31;
        BCs[tt][col] = x_dbl[(size_t)(b * SEQLEN + t0 + tt) * XCOLS + DT_RANK + col];
    }
    float A_row[D_STATE];
    #pragma unroll
    for (int n = 0; n < D_STATE; ++n)
        A_row[n] = -__expf(A_log[d * D_STATE + n]);
    const float bdt = b_dt[d];
    const float Dd = Dvec[d];
    __syncthreads();
    float h[D_STATE];
    const size_t base = ((size_t)(b * NCHUNK + c) * D_STATE) * D_INNER + d;
    #pragma unroll
    for (int n = 0; n < D_STATE; ++n) h[n] = hin[base + (size_t)n * D_INNER];
    const float* dpp = dt_pre + (size_t)(b * SEQLEN + t0) * D_INNER + d;
    const float* upp = u + (size_t)(b * SEQLEN + t0) * D_INNER + d;
    const float* zpp = xz + (size_t)(b * SEQLEN + t0) * (2 * D_INNER) + D_INNER + d;
    bf16* gpp = g_bf + (size_t)(b * SEQLEN + t0) * D_INNER + d;
    #pragma unroll
    for (int t = 0; t < LCHUNK; ++t) {
        float xv = dpp[(size_t)t * D_INNER] + bdt;
        float dtv = softplus_f(xv);
        float uv = upp[(size_t)t * D_INNER];
        float zv = zpp[(size_t)t * 2 * D_INNER];
        float du = dtv * uv;
        float y = 0.f;
        const float4* bc4 = (const float4*)&BCs[t][0];
        #pragma unroll
        for (int q = 0; q < 4; ++q) {
            float4 v = bc4[q];
            float4 w = bc4[q + 4];
            float Bn[4] = {v.x, v.y, v.z, v.w};
            float Cn[4] = {w.x, w.y, w.z, w.w};
            #pragma unroll
            for (int e = 0; e < 4; ++e) {
                int n = q * 4 + e;
                float a = __expf(dtv * A_row[n]);
                h[n] = fmaf(a, h[n], du * Bn[e]);
                y = fmaf(h[n], Cn[e], y);
            }
        }
        float gy = y + uv * Dd;
        float sz = zv / (1.f + __expf(-zv));
        gpp[(size_t)t * D_INNER] = __float2bfloat16(gy * sz);
    }
}

extern "C" void kernel_launch(void* const* d_in, const int* in_sizes, int n_in,
                              void* d_out, int out_size, void* d_ws, size_t ws_size,
                              hipStream_t stream)
{
    const float* x      = (const float*)d_in[0];
    const float* W_in   = (const float*)d_in[1];
    const float* conv_k = (const float*)d_in[2];
    const float* conv_b = (const float*)d_in[3];
    const float* W_xproj= (const float*)d_in[4];
    const float* W_dt   = (const float*)d_in[5];
    const float* b_dt   = (const float*)d_in[6];
    const float* A_log  = (const float*)d_in[7];
    const float* Dvec   = (const float*)d_in[8];
    const float* W_out  = (const float*)d_in[9];
    float* out = (float*)d_out;

    const int BL = BATCH * SEQLEN;                    // 2048

    // fp32 intermediates
    float* ws     = (float*)d_ws;
    float* xz     = ws;                                 // 8,388,608
    float* u      = xz     + (size_t)BL * 2 * D_INNER;  // 4,194,304
    float* x_dbl  = u      + (size_t)BL * D_INNER;      //   327,680
    float* dt_pre = x_dbl  + (size_t)BL * XCOLS;        // 4,194,304
    float* Pst    = dt_pre + (size_t)BL * D_INNER;      // 4,194,304 (alias: Cpart3 / Cpart6 half)
    float* Sst    = Pst    + (size_t)BATCH * NCHUNK * D_STATE * D_INNER; // 4,194,304 (alias: x_bf, Cpart6 half)
    float* Cpart3 = Pst;                                // 8 x 2048 x 256
    float* Cpart6 = Pst;                                // 2 x 2048 x 1024 (spans Pst+Sst)
    bf16*  x_bf   = (bf16*)Sst;                         // 2048 x 1024 (used only before phase1)
    // bf16 buffers
    bf16* Win_t  = (bf16*)(Sst + (size_t)BATCH * NCHUNK * D_STATE * D_INNER);
    bf16* u_bf   = Win_t + (size_t)4096 * 1024;         // 2048 x 2048
    bf16* Wxp_t  = u_bf  + (size_t)BL * D_INNER;        // 256  x 2048 (padded)
    bf16* dtA_bf = Wxp_t + (size_t)256 * 2048;          // 2048 x 128
    bf16* Wdt_t  = dtA_bf+ (size_t)BL * DT_RANK;        // 2048 x 128
    bf16* g_bf   = Wdt_t + (size_t)2048 * 128;          // 2048 x 2048
    bf16* Wout_t = g_bf  + (size_t)BL * D_INNER;        // 1024 x 2048

    // 0) converts / transposes
    convert_f32_bf16<<<(BL * D_MODEL) / 256, 256, 0, stream>>>(x, x_bf, BL * D_MODEL);
    transpose_f32_bf16<<<dim3(4096 / 32, 1024 / 32), 256, 0, stream>>>(W_in, Win_t, D_MODEL, 2 * D_INNER);
    transpose_f32_bf16<<<dim3(256 / 32, 2048 / 32), 256, 0, stream>>>(W_xproj, Wxp_t, D_INNER, XCOLS);
    transpose_f32_bf16<<<dim3(2048 / 32, 128 / 32), 256, 0, stream>>>(W_dt, Wdt_t, DT_RANK, D_INNER);
    transpose_f32_bf16<<<dim3(1024 / 32, 2048 / 32), 256, 0, stream>>>(W_out, Wout_t, D_INNER, D_MODEL);

    // 1) xz = x @ W_in            (2048x1024)@(1024x4096)
    gemm_mfma_bt<<<dim3(32, 16, 1), 256, 0, stream>>>(
        x_bf, Win_t, xz, BL, 2 * D_INNER, D_MODEL, 2 * D_INNER, D_MODEL);

    // 2) u = silu(causal_conv(xz[:, :2048]) + b)  (+ bf16 mirror)
    conv_silu_kernel<<<(BL * D_INNER / 4) / 256, 256, 0, stream>>>(xz, conv_k, conv_b, u, u_bf);

    // 3) x_dbl = u @ W_xproj  split-K 8  (2048x2048)@(2048x160->256)
    gemm_mfma_bt<<<dim3(2, 16, 8), 256, 0, stream>>>(
        u_bf, Wxp_t, Cpart3, BL, 256, D_INNER, 256, 256);
    reduce_xdbl<<<(BL * XCOLS + 255) / 256, 256, 0, stream>>>(Cpart3, x_dbl, dtA_bf);

    // 4) dt_pre = dt_low @ W_dt   (2048x128)@(128x2048)
    gemm_mfma_bt<<<dim3(16, 16, 1), 256, 0, stream>>>(
        dtA_bf, Wdt_t, dt_pre, BL, D_INNER, DT_RANK, D_INNER, DT_RANK);

    // 5) chunked selective scan -> g_bf = bf16((y + u*D) * silu(z))
    scan_phase1<<<dim3(D_INNER / 256, NCHUNK, BATCH), 256, 0, stream>>>(
        dt_pre, b_dt, A_log, u, x_dbl, Pst, Sst);
    scan_phase2<<<dim3(D_INNER / 256, D_STATE, BATCH), 256, 0, stream>>>(Pst, Sst);
    scan_phase3<<<dim3(D_INNER / 256, NCHUNK, BATCH), 256, 0, stream>>>(
        dt_pre, b_dt, A_log, u, x_dbl, Dvec, xz, Sst, g_bf);

    // 6) out = g @ W_out  split-K 2  (2048x2048)@(2048x1024)
    gemm_mfma_bt<<<dim3(8, 16, 2), 256, 0, stream>>>(
        g_bf, Wout_t, Cpart6, BL, D_MODEL, D_INNER, D_MODEL, D_MODEL);
    reduce_out<<<(BL * D_MODEL / 4) / 256, 256, 0, stream>>>(Cpart6, out);
}

// Round 6
// 244.279 us; speedup vs baseline: 10.0389x; 1.0640x over previous
//
#include <hip/hip_runtime.h>
#include <hip/hip_bf16.h>

#define D_MODEL 1024
#define D_STATE 16
#define D_CONV 4
#define D_INNER 2048
#define DT_RANK 128
#define BATCH 2
#define SEQLEN 1024
#define XCOLS 160     // DT_RANK + 2*D_STATE
#define NCHUNK 64
#define LCHUNK 16     // SEQLEN / NCHUNK

typedef __hip_bfloat16 bf16;
typedef __attribute__((ext_vector_type(8))) short short8;
typedef __attribute__((ext_vector_type(4))) float f32x4;

__device__ __forceinline__ unsigned short f2bf_bits(float f) {
    bf16 h = __float2bfloat16(f);
    return *(unsigned short*)&h;
}

__device__ __forceinline__ float softplus_f(float x) {
    return fmaxf(x, 0.f) + __logf(1.f + __expf(-fabsf(x)));
}

// async global->LDS 16B per lane; LDS dest must be lane-contiguous per wave.
__device__ __forceinline__ void load16_lds(void* lds, const void* g) {
    __builtin_amdgcn_global_load_lds(
        (const __attribute__((address_space(1))) unsigned int*)g,
        (__attribute__((address_space(3))) unsigned int*)lds, 16, 0, 0);
}

// ---------------- fused prep: weight transposes + x convert + A precompute ----
__device__ __forceinline__ void transpose_tile(const float* __restrict__ B,
                                               bf16* __restrict__ Bt,
                                               int K, int N, int nt, int kt,
                                               float (*t)[33], int tid)
{
    const int tx = tid & 31, ty = tid >> 5;
    const int n0 = nt * 32, k0 = kt * 32;
    #pragma unroll
    for (int r = 0; r < 4; ++r) {
        int n = n0 + tx;
        t[ty + r * 8][tx] = (n < N) ? B[(size_t)(k0 + ty + r * 8) * N + n] : 0.f;
    }
    __syncthreads();
    #pragma unroll
    for (int r = 0; r < 4; ++r)
        Bt[(size_t)(n0 + ty + r * 8) * K + k0 + tx] = __float2bfloat16(t[tx][ty + r * 8]);
}

__global__ __launch_bounds__(256)
void prep_kernel(const float* __restrict__ x, bf16* __restrict__ x_bf,
                 const float* __restrict__ W_in, bf16* __restrict__ Win_t,
                 const float* __restrict__ W_xproj, bf16* __restrict__ Wxp_t,
                 const float* __restrict__ W_dt, bf16* __restrict__ Wdt_t,
                 const float* __restrict__ W_out, bf16* __restrict__ Wout_t,
                 const float* __restrict__ A_log, float* __restrict__ Aneg)
{
    __shared__ float t[32][33];
    const int tid = threadIdx.x;
    int blk = blockIdx.x;
    if (blk < 4096) {            // W_in: K=1024, Npad=4096 -> 128 x 32 tiles
        transpose_tile(W_in, Win_t, D_MODEL, 2 * D_INNER, blk & 127, blk >> 7, t, tid);
        return;
    }
    blk -= 4096;
    if (blk < 512) {             // W_xproj: K=2048, Npad=256 -> 8 x 64 tiles
        transpose_tile(W_xproj, Wxp_t, D_INNER, XCOLS, blk & 7, blk >> 3, t, tid);
        return;
    }
    blk -= 512;
    if (blk < 256) {             // W_dt: K=128, N=2048 -> 64 x 4 tiles
        transpose_tile(W_dt, Wdt_t, DT_RANK, D_INNER, blk & 63, blk >> 6, t, tid);
        return;
    }
    blk -= 256;
    if (blk < 2048) {            // W_out: K=2048, N=1024 -> 32 x 64 tiles
        transpose_tile(W_out, Wout_t, D_INNER, D_MODEL, blk & 31, blk >> 5, t, tid);
        return;
    }
    blk -= 2048;
    if (blk < 2048) {            // x -> bf16, float4 (2048*256*4 = 2,097,152)
        int i = blk * 256 + tid;
        float4 v = ((const float4*)x)[i];
        ushort4 p;
        p.x = f2bf_bits(v.x); p.y = f2bf_bits(v.y);
        p.z = f2bf_bits(v.z); p.w = f2bf_bits(v.w);
        ((ushort4*)x_bf)[i] = p;
        return;
    }
    blk -= 2048;
    {                            // Aneg = -exp(A_log), 32768 elems -> 128 blocks
        int i = blk * 256 + tid;
        Aneg[i] = -__expf(A_log[i]);
    }
}

// ---------------- MFMA GEMM (split-K capable, async LDS staging) -------------
// C_z[M,ldc] = A[M,kchunk] @ Bt[Npad,kchunk]^T, chunk z = blockIdx.z.
// 128x128 tile, BK=32, 256 threads (4 waves), wave = 64x64 via 4x4 of 16x16x32.
// EPI=0: plain fp32 store. EPI=1: store softplus(acc + bias[col]).
template<int EPI>
__global__ __launch_bounds__(256)
void gemm_mfma_bt(const bf16* __restrict__ A, const bf16* __restrict__ Bt,
                  float* __restrict__ C, const float* __restrict__ bias,
                  int M, int N, int K, int ldc, int kchunk)
{
    __shared__ short As[128 * 32];
    __shared__ short Bs[128 * 32];
    const int tid = threadIdx.x;
    const int lane = tid & 63, wave = tid >> 6;
    const int wm = (wave >> 1) * 64, wn = (wave & 1) * 64;
    const int row0 = blockIdx.y * 128, col0 = blockIdx.x * 128;
    const int r_m = lane & 15, r_q = lane >> 4;
    const int kstart = blockIdx.z * kchunk;
    float* Cz = C + (size_t)blockIdx.z * M * ldc;

    // staging: thread t covers LDS short-index 8*tid (+2048), i.e. byte 16*tid:
    // per wave lane-contiguous => valid global_load_lds destination.
    const int srow = tid >> 2, schk = (tid & 3) * 8;
    const bf16* Ag0 = A  + (size_t)(row0 + srow)      * K + kstart + schk;
    const bf16* Ag1 = A  + (size_t)(row0 + srow + 64) * K + kstart + schk;
    const bf16* Bg0 = Bt + (size_t)(col0 + srow)      * K + kstart + schk;
    const bf16* Bg1 = Bt + (size_t)(col0 + srow + 64) * K + kstart + schk;
    short* AsW0 = &As[8 * tid];
    short* AsW1 = &As[8 * tid + 2048];
    short* BsW0 = &Bs[8 * tid];
    short* BsW1 = &Bs[8 * tid + 2048];

    f32x4 acc[4][4];
    #pragma unroll
    for (int i = 0; i < 4; ++i)
        #pragma unroll
        for (int j = 0; j < 4; ++j)
            #pragma unroll
            for (int r = 0; r < 4; ++r) acc[i][j][r] = 0.f;

    for (int k0 = 0; k0 < kchunk; k0 += 32) {
        __syncthreads();                 // prev-iter LDS reads done
        load16_lds(AsW0, Ag0 + k0);
        load16_lds(AsW1, Ag1 + k0);
        load16_lds(BsW0, Bg0 + k0);
        load16_lds(BsW1, Bg1 + k0);
        __syncthreads();                 // drains vmcnt -> staging visible
        short8 af[4], bfr[4];
        #pragma unroll
        for (int i = 0; i < 4; ++i)
            af[i] = *(const short8*)&As[(wm + i * 16 + r_m) * 32 + r_q * 8];
        #pragma unroll
        for (int j = 0; j < 4; ++j)
            bfr[j] = *(const short8*)&Bs[(wn + j * 16 + r_m) * 32 + r_q * 8];
        #pragma unroll
        for (int i = 0; i < 4; ++i)
            #pragma unroll
            for (int j = 0; j < 4; ++j)
                acc[i][j] = __builtin_amdgcn_mfma_f32_16x16x32_bf16(
                    af[i], bfr[j], acc[i][j], 0, 0, 0);
    }

    #pragma unroll
    for (int i = 0; i < 4; ++i) {
        #pragma unroll
        for (int j = 0; j < 4; ++j) {
            int row = row0 + wm + i * 16 + r_q * 4;
            int col = col0 + wn + j * 16 + r_m;
            if (col < N) {
                if (EPI == 1) {
                    float bv = bias[col];
                    #pragma unroll
                    for (int r = 0; r < 4; ++r)
                        Cz[(size_t)(row + r) * ldc + col] =
                            softplus_f(acc[i][j][r] + bv);
                } else {
                    #pragma unroll
                    for (int r = 0; r < 4; ++r)
                        Cz[(size_t)(row + r) * ldc + col] = acc[i][j][r];
                }
            }
        }
    }
}

// reduce 8 split-K partials (ldc=256) -> x_dbl fp32 (160 cols) + dt_low bf16
__global__ __launch_bounds__(256)
void reduce_xdbl(const float* __restrict__ Cpart, float* __restrict__ x_dbl,
                 bf16* __restrict__ dtA_bf)
{
    int i = blockIdx.x * 256 + threadIdx.x;          // 2048*160
    if (i >= 2048 * XCOLS) return;
    int r = i / XCOLS, c = i - r * XCOLS;
    float s = 0.f;
    #pragma unroll
    for (int z = 0; z < 8; ++z)
        s += Cpart[(size_t)z * 2048 * 256 + (size_t)r * 256 + c];
    x_dbl[i] = s;
    if (c < DT_RANK) dtA_bf[(size_t)r * DT_RANK + c] = __float2bfloat16(s);
}

// reduce 2 split-K partials -> out fp32, float4
__global__ __launch_bounds__(256)
void reduce_out(const float* __restrict__ Cpart, float* __restrict__ out)
{
    int i = blockIdx.x * 256 + threadIdx.x;          // (2048*1024)/4
    const float4* p0 = (const float4*)Cpart;
    const float4* p1 = p0 + (size_t)2048 * 1024 / 4;
    float4 a = p0[i], b = p1[i];
    float4 r; r.x = a.x + b.x; r.y = a.y + b.y; r.z = a.z + b.z; r.w = a.w + b.w;
    ((float4*)out)[i] = r;
}

// ---------------- conv + silu (float4 over d), bf16 output only --------------
__global__ __launch_bounds__(256)
void conv_silu_kernel(const float* __restrict__ xz,
                      const float* __restrict__ conv_k,
                      const float* __restrict__ conv_b,
                      bf16* __restrict__ u_bf)
{
    int idx4 = blockIdx.x * 256 + threadIdx.x;       // B*L*Di/4 = 1048576
    int d4 = idx4 & (D_INNER / 4 - 1);
    int t = (idx4 >> 9) & (SEQLEN - 1);
    int b = idx4 >> 19;
    float4 acc = ((const float4*)conv_b)[d4];
    #pragma unroll
    for (int k = 0; k < D_CONV; ++k) {
        int tt = t + k - (D_CONV - 1);
        if (tt >= 0) {
            float4 xv = ((const float4*)xz)[(size_t)(b * SEQLEN + tt) * (2 * D_INNER / 4) + d4];
            float4 kv = ((const float4*)conv_k)[k * (D_INNER / 4) + d4];
            acc.x = fmaf(xv.x, kv.x, acc.x);
            acc.y = fmaf(xv.y, kv.y, acc.y);
            acc.z = fmaf(xv.z, kv.z, acc.z);
            acc.w = fmaf(xv.w, kv.w, acc.w);
        }
    }
    ushort4 pk;
    pk.x = f2bf_bits(acc.x / (1.f + __expf(-acc.x)));
    pk.y = f2bf_bits(acc.y / (1.f + __expf(-acc.y)));
    pk.z = f2bf_bits(acc.z / (1.f + __expf(-acc.z)));
    pk.w = f2bf_bits(acc.w / (1.f + __expf(-acc.w)));
    ((ushort4*)u_bf)[idx4] = pk;
}

// ---------------- chunked scan ----------------
// dt_s already has softplus(dt_pre + b_dt) applied (GEMM4 epilogue).
__global__ __launch_bounds__(256)
void scan_phase1(const float* __restrict__ dt_s,
                 const float* __restrict__ Aneg,
                 const bf16* __restrict__ u_bf,
                 const float* __restrict__ x_dbl,
                 float* __restrict__ Pst, float* __restrict__ Sst)
{
    __shared__ float Bsm[LCHUNK][16];
    const int d = blockIdx.x * 256 + threadIdx.x;
    const int c = blockIdx.y, b = blockIdx.z;
    const int t0 = c * LCHUNK;
    {   // stage B rows (shared by all d in block)
        int tt = threadIdx.x >> 4, n = threadIdx.x & 15;
        Bsm[tt][n] = x_dbl[(size_t)(b * SEQLEN + t0 + tt) * XCOLS + DT_RANK + n];
    }
    float A_row[D_STATE];
    const float4* a4 = (const float4*)(Aneg + d * D_STATE);
    #pragma unroll
    for (int q = 0; q < 4; ++q) {
        float4 v = a4[q];
        A_row[q*4+0] = v.x; A_row[q*4+1] = v.y; A_row[q*4+2] = v.z; A_row[q*4+3] = v.w;
    }
    __syncthreads();
    float P[D_STATE], S[D_STATE];
    #pragma unroll
    for (int n = 0; n < D_STATE; ++n) { P[n] = 1.f; S[n] = 0.f; }
    const float* dpp = dt_s + (size_t)(b * SEQLEN + t0) * D_INNER + d;
    const bf16* upp = u_bf + (size_t)(b * SEQLEN + t0) * D_INNER + d;
    #pragma unroll
    for (int t = 0; t < LCHUNK; ++t) {
        float dtv = dpp[(size_t)t * D_INNER];
        float du = dtv * __bfloat162float(upp[(size_t)t * D_INNER]);
        const float4* b4 = (const float4*)&Bsm[t][0];
        #pragma unroll
        for (int q = 0; q < 4; ++q) {
            float4 v = b4[q];
            float Bn[4] = {v.x, v.y, v.z, v.w};
            #pragma unroll
            for (int e = 0; e < 4; ++e) {
                int n = q * 4 + e;
                float a = __expf(dtv * A_row[n]);
                P[n] *= a;
                S[n] = fmaf(a, S[n], du * Bn[e]);
            }
        }
    }
    const size_t base = ((size_t)(b * NCHUNK + c) * D_STATE) * D_INNER + d;
    #pragma unroll
    for (int n = 0; n < D_STATE; ++n) {
        Pst[base + (size_t)n * D_INNER] = P[n];
        Sst[base + (size_t)n * D_INNER] = S[n];
    }
}

// Phase 2: combine chunk transforms; write h_in per chunk IN-PLACE over Sst.
__global__ __launch_bounds__(256)
void scan_phase2(const float* __restrict__ Pst, float* __restrict__ Sst)
{
    const int d = blockIdx.x * 256 + threadIdx.x;
    const int n = blockIdx.y;
    const int b = blockIdx.z;
    float h = 0.f;
    for (int c = 0; c < NCHUNK; ++c) {
        const size_t idx = ((size_t)(b * NCHUNK + c) * D_STATE + n) * D_INNER + d;
        float Pv = Pst[idx], Sv = Sst[idx];
        Sst[idx] = h;                       // h_in for chunk c
        h = fmaf(Pv, h, Sv);
    }
}

__global__ __launch_bounds__(256)
void scan_phase3(const float* __restrict__ dt_s,
                 const float* __restrict__ Aneg,
                 const bf16* __restrict__ u_bf,
                 const float* __restrict__ x_dbl,
                 const float* __restrict__ Dvec,
                 const float* __restrict__ xz,
                 const float* __restrict__ hin,   // == Sst after phase2
                 bf16* __restrict__ g_bf)
{
    __shared__ float BCs[LCHUNK][32];
    const int d = blockIdx.x * 256 + threadIdx.x;
    const int c = blockIdx.y, b = blockIdx.z;
    const int t0 = c * LCHUNK;
    {   // stage B and C rows
        int i0 = threadIdx.x;
        int tt = i0 >> 5, col = i0 & 31;
        BCs[tt][col] = x_dbl[(size_t)(b * SEQLEN + t0 + tt) * XCOLS + DT_RANK + col];
        int i1 = i0 + 256;
        tt = i1 >> 5; col = i1 & 31;
        BCs[tt][col] = x_dbl[(size_t)(b * SEQLEN + t0 + tt) * XCOLS + DT_RANK + col];
    }
    float A_row[D_STATE];
    const float4* a4 = (const float4*)(Aneg + d * D_STATE);
    #pragma unroll
    for (int q = 0; q < 4; ++q) {
        float4 v = a4[q];
        A_row[q*4+0] = v.x; A_row[q*4+1] = v.y; A_row[q*4+2] = v.z; A_row[q*4+3] = v.w;
    }
    const float Dd = Dvec[d];
    __syncthreads();
    float h[D_STATE];
    const size_t base = ((size_t)(b * NCHUNK + c) * D_STATE) * D_INNER + d;
    #pragma unroll
    for (int n = 0; n < D_STATE; ++n) h[n] = hin[base + (size_t)n * D_INNER];
    const float* dpp = dt_s + (size_t)(b * SEQLEN + t0) * D_INNER + d;
    const bf16* upp = u_bf + (size_t)(b * SEQLEN + t0) * D_INNER + d;
    const float* zpp = xz + (size_t)(b * SEQLEN + t0) * (2 * D_INNER) + D_INNER + d;
    bf16* gpp = g_bf + (size_t)(b * SEQLEN + t0) * D_INNER + d;
    #pragma unroll
    for (int t = 0; t < LCHUNK; ++t) {
        float dtv = dpp[(size_t)t * D_INNER];
        float uv = __bfloat162float(upp[(size_t)t * D_INNER]);
        float zv = zpp[(size_t)t * 2 * D_INNER];
        float du = dtv * uv;
        float y = 0.f;
        const float4* bc4 = (const float4*)&BCs[t][0];
        #pragma unroll
        for (int q = 0; q < 4; ++q) {
            float4 v = bc4[q];
            float4 w = bc4[q + 4];
            float Bn[4] = {v.x, v.y, v.z, v.w};
            float Cn[4] = {w.x, w.y, w.z, w.w};
            #pragma unroll
            for (int e = 0; e < 4; ++e) {
                int n = q * 4 + e;
                float a = __expf(dtv * A_row[n]);
                h[n] = fmaf(a, h[n], du * Bn[e]);
                y = fmaf(h[n], Cn[e], y);
            }
        }
        float gy = y + uv * Dd;
        float sz = zv / (1.f + __expf(-zv));
        gpp[(size_t)t * D_INNER] = __float2bfloat16(gy * sz);
    }
}

extern "C" void kernel_launch(void* const* d_in, const int* in_sizes, int n_in,
                              void* d_out, int out_size, void* d_ws, size_t ws_size,
                              hipStream_t stream)
{
    const float* x      = (const float*)d_in[0];
    const float* W_in   = (const float*)d_in[1];
    const float* conv_k = (const float*)d_in[2];
    const float* conv_b = (const float*)d_in[3];
    const float* W_xproj= (const float*)d_in[4];
    const float* W_dt   = (const float*)d_in[5];
    const float* b_dt   = (const float*)d_in[6];
    const float* A_log  = (const float*)d_in[7];
    const float* Dvec   = (const float*)d_in[8];
    const float* W_out  = (const float*)d_in[9];
    float* out = (float*)d_out;

    const int BL = BATCH * SEQLEN;                    // 2048

    // fp32 region
    float* ws     = (float*)d_ws;
    float* xz     = ws;                                 // 8,388,608
    float* x_dbl  = xz     + (size_t)BL * 2 * D_INNER;  //   327,680
    float* dt_s   = x_dbl  + (size_t)BL * XCOLS;        // 4,194,304
    float* Pst    = dt_s   + (size_t)BL * D_INNER;      // 4,194,304
    float* Sst    = Pst    + (size_t)BATCH * NCHUNK * D_STATE * D_INNER; // 4,194,304
    float* Aneg   = Sst    + (size_t)BATCH * NCHUNK * D_STATE * D_INNER; // 32,768
    float* Cpart3 = Pst;                                // 8 x 2048 x 256 (dead region)
    float* Cpart6 = Pst;                                // 2 x 2048 x 1024 (spans Pst+Sst; Pst dead, Sst... )
    // NOTE: Cpart6 must not clobber Sst (hin is dead after phase3, Pst after phase2).
    // 2*2048*1024 = 4,194,304 floats fits entirely in Pst. Point second half there too.
    bf16*  x_bf   = (bf16*)Sst;                         // 2048x1024, dead before phase1
    // bf16 region
    bf16* Win_t  = (bf16*)(Aneg + 32768);
    bf16* u_bf   = Win_t + (size_t)4096 * 1024;         // 2048 x 2048
    bf16* Wxp_t  = u_bf  + (size_t)BL * D_INNER;        // 256  x 2048 (padded)
    bf16* dtA_bf = Wxp_t + (size_t)256 * 2048;          // 2048 x 128
    bf16* Wdt_t  = dtA_bf+ (size_t)BL * DT_RANK;        // 2048 x 128
    bf16* g_bf   = Wdt_t + (size_t)2048 * 128;          // 2048 x 2048
    bf16* Wout_t = g_bf  + (size_t)BL * D_INNER;        // 1024 x 2048

    // 0) fused prep: 4 transposes + x convert + Aneg
    prep_kernel<<<4096 + 512 + 256 + 2048 + 2048 + 128, 256, 0, stream>>>(
        x, x_bf, W_in, Win_t, W_xproj, Wxp_t, W_dt, Wdt_t, W_out, Wout_t, A_log, Aneg);

    // 1) xz = x @ W_in            (2048x1024)@(1024x4096)
    gemm_mfma_bt<0><<<dim3(32, 16, 1), 256, 0, stream>>>(
        x_bf, Win_t, xz, nullptr, BL, 2 * D_INNER, D_MODEL, 2 * D_INNER, D_MODEL);

    // 2) u_bf = bf16(silu(causal_conv(xz[:, :2048]) + b))
    conv_silu_kernel<<<(BL * D_INNER / 4) / 256, 256, 0, stream>>>(xz, conv_k, conv_b, u_bf);

    // 3) x_dbl = u @ W_xproj  split-K 8  (2048x2048)@(2048x160->256)
    gemm_mfma_bt<0><<<dim3(2, 16, 8), 256, 0, stream>>>(
        u_bf, Wxp_t, Cpart3, nullptr, BL, 256, D_INNER, 256, 256);
    reduce_xdbl<<<(BL * XCOLS + 255) / 256, 256, 0, stream>>>(Cpart3, x_dbl, dtA_bf);

    // 4) dt_s = softplus(dt_low @ W_dt + b_dt)   (2048x128)@(128x2048)
    gemm_mfma_bt<1><<<dim3(16, 16, 1), 256, 0, stream>>>(
        dtA_bf, Wdt_t, dt_s, b_dt, BL, D_INNER, DT_RANK, D_INNER, DT_RANK);

    // 5) chunked selective scan -> g_bf = bf16((y + u*D) * silu(z))
    scan_phase1<<<dim3(D_INNER / 256, NCHUNK, BATCH), 256, 0, stream>>>(
        dt_s, Aneg, u_bf, x_dbl, Pst, Sst);
    scan_phase2<<<dim3(D_INNER / 256, D_STATE, BATCH), 256, 0, stream>>>(Pst, Sst);
    scan_phase3<<<dim3(D_INNER / 256, NCHUNK, BATCH), 256, 0, stream>>>(
        dt_s, Aneg, u_bf, x_dbl, Dvec, xz, Sst, g_bf);

    // 6) out = g @ W_out  split-K 2  (2048x2048)@(2048x1024)
    gemm_mfma_bt<0><<<dim3(8, 16, 2), 256, 0, stream>>>(
        g_bf, Wout_t, Cpart6, nullptr, BL, D_MODEL, D_INNER, D_MODEL, D_MODEL);
    reduce_out<<<(BL * D_MODEL / 4) / 256, 256, 0, stream>>>(Cpart6, out);
}

// Round 7
// 235.822 us; speedup vs baseline: 10.3989x; 1.0359x over previous
//
#include <hip/hip_runtime.h>
#include <hip/hip_bf16.h>

#define D_MODEL 1024
#define D_STATE 16
#define D_CONV 4
#define D_INNER 2048
#define DT_RANK 128
#define BATCH 2
#define SEQLEN 1024
#define XCOLS 160     // DT_RANK + 2*D_STATE
#define NCHUNK 64
#define LCHUNK 16     // SEQLEN / NCHUNK

typedef __hip_bfloat16 bf16;
typedef __attribute__((ext_vector_type(8))) short short8;
typedef __attribute__((ext_vector_type(4))) float f32x4;

__device__ __forceinline__ unsigned short f2bf_bits(float f) {
    bf16 h = __float2bfloat16(f);
    return *(unsigned short*)&h;
}

__device__ __forceinline__ float softplus_f(float x) {
    return fmaxf(x, 0.f) + __logf(1.f + __expf(-fabsf(x)));
}

// async global->LDS 16B per lane; LDS dest must be wave-uniform base + lane*16.
__device__ __forceinline__ void load16_lds(void* lds, const void* g) {
    __builtin_amdgcn_global_load_lds(
        (const __attribute__((address_space(1))) unsigned int*)g,
        (__attribute__((address_space(3))) unsigned int*)lds, 16, 0, 0);
}

// ---------------- fused prep: weight transposes + x convert + A precompute ----
__device__ __forceinline__ void transpose_tile(const float* __restrict__ B,
                                               bf16* __restrict__ Bt,
                                               int K, int N, int nt, int kt,
                                               float (*t)[33], int tid)
{
    const int tx = tid & 31, ty = tid >> 5;
    const int n0 = nt * 32, k0 = kt * 32;
    #pragma unroll
    for (int r = 0; r < 4; ++r) {
        int n = n0 + tx;
        t[ty + r * 8][tx] = (n < N) ? B[(size_t)(k0 + ty + r * 8) * N + n] : 0.f;
    }
    __syncthreads();
    #pragma unroll
    for (int r = 0; r < 4; ++r)
        Bt[(size_t)(n0 + ty + r * 8) * K + k0 + tx] = __float2bfloat16(t[tx][ty + r * 8]);
}

__global__ __launch_bounds__(256)
void prep_kernel(const float* __restrict__ x, bf16* __restrict__ x_bf,
                 const float* __restrict__ W_in, bf16* __restrict__ Win_t,
                 const float* __restrict__ W_xproj, bf16* __restrict__ Wxp_t,
                 const float* __restrict__ W_dt, bf16* __restrict__ Wdt_t,
                 const float* __restrict__ W_out, bf16* __restrict__ Wout_t,
                 const float* __restrict__ A_log, float* __restrict__ Aneg)
{
    __shared__ float t[32][33];
    const int tid = threadIdx.x;
    int blk = blockIdx.x;
    if (blk < 4096) {            // W_in: K=1024, Npad=4096 -> 128 x 32 tiles
        transpose_tile(W_in, Win_t, D_MODEL, 2 * D_INNER, blk & 127, blk >> 7, t, tid);
        return;
    }
    blk -= 4096;
    if (blk < 512) {             // W_xproj: K=2048, Npad=256 -> 8 x 64 tiles
        transpose_tile(W_xproj, Wxp_t, D_INNER, XCOLS, blk & 7, blk >> 3, t, tid);
        return;
    }
    blk -= 512;
    if (blk < 256) {             // W_dt: K=128, N=2048 -> 64 x 4 tiles
        transpose_tile(W_dt, Wdt_t, DT_RANK, D_INNER, blk & 63, blk >> 6, t, tid);
        return;
    }
    blk -= 256;
    if (blk < 2048) {            // W_out: K=2048, N=1024 -> 32 x 64 tiles
        transpose_tile(W_out, Wout_t, D_INNER, D_MODEL, blk & 31, blk >> 5, t, tid);
        return;
    }
    blk -= 2048;
    if (blk < 2048) {            // x -> bf16, float4
        int i = blk * 256 + tid;
        float4 v = ((const float4*)x)[i];
        ushort4 p;
        p.x = f2bf_bits(v.x); p.y = f2bf_bits(v.y);
        p.z = f2bf_bits(v.z); p.w = f2bf_bits(v.w);
        ((ushort4*)x_bf)[i] = p;
        return;
    }
    blk -= 2048;
    {                            // Aneg = -exp(A_log)
        int i = blk * 256 + tid;
        Aneg[i] = -__expf(A_log[i]);
    }
}

// ---------------- MFMA GEMM (tile 128xBN, BK=32, split-K capable) ------------
// C_z[M,ldc] = A[M,kchunk] @ Bt[Npad,kchunk]^T, chunk z = blockIdx.z.
// 256 threads (4 waves). BN=128: wave=64x64 (4x4 mfma). BN=64: wave=64x32 (4x2).
// EPI=0: fp32 store to C. EPI=1: bf16 store of softplus(acc + bias[col]) to Cb.
template<int BN, int EPI>
__global__ __launch_bounds__(256)
void gemm_mfma(const bf16* __restrict__ A, const bf16* __restrict__ Bt,
               float* __restrict__ C, bf16* __restrict__ Cb,
               const float* __restrict__ bias,
               int M, int N, int K, int ldc, int kchunk)
{
    constexpr int WN = (BN == 128) ? 64 : 32;
    constexpr int NJ = WN / 16;
    __shared__ short As[128 * 32];
    __shared__ short Bs[BN * 32];
    const int tid = threadIdx.x;
    const int lane = tid & 63, wave = tid >> 6;
    const int wm = (wave >> 1) * 64, wn = (wave & 1) * WN;
    const int row0 = blockIdx.y * 128, col0 = blockIdx.x * BN;
    const int r_m = lane & 15, r_q = lane >> 4;
    const int kstart = blockIdx.z * kchunk;
    float* Cz = C + (size_t)blockIdx.z * M * ldc;

    // staging: thread t -> LDS byte 16*tid (wave-uniform base + lane*16)
    const int srow = tid >> 2, schk = (tid & 3) * 8;
    const bf16* Ag0 = A  + (size_t)(row0 + srow)      * K + kstart + schk;
    const bf16* Ag1 = A  + (size_t)(row0 + srow + 64) * K + kstart + schk;
    const bf16* Bg0 = Bt + (size_t)(col0 + srow)      * K + kstart + schk;
    const bf16* Bg1 = Bt + (size_t)(col0 + srow + 64) * K + kstart + schk; // BN=128 only
    short* AsW0 = &As[8 * tid];
    short* AsW1 = &As[8 * tid + 2048];
    short* BsW0 = &Bs[8 * tid];
    short* BsW1 = &Bs[8 * tid + 2048];

    f32x4 acc[4][NJ];
    #pragma unroll
    for (int i = 0; i < 4; ++i)
        #pragma unroll
        for (int j = 0; j < NJ; ++j)
            #pragma unroll
            for (int r = 0; r < 4; ++r) acc[i][j][r] = 0.f;

    for (int k0 = 0; k0 < kchunk; k0 += 32) {
        __syncthreads();                 // prev-iter LDS reads done
        load16_lds(AsW0, Ag0 + k0);
        load16_lds(AsW1, Ag1 + k0);
        load16_lds(BsW0, Bg0 + k0);
        if (BN == 128) load16_lds(BsW1, Bg1 + k0);
        __syncthreads();                 // drains vmcnt -> staging visible
        short8 af[4], bfr[NJ];
        #pragma unroll
        for (int i = 0; i < 4; ++i)
            af[i] = *(const short8*)&As[(wm + i * 16 + r_m) * 32 + r_q * 8];
        #pragma unroll
        for (int j = 0; j < NJ; ++j)
            bfr[j] = *(const short8*)&Bs[(wn + j * 16 + r_m) * 32 + r_q * 8];
        #pragma unroll
        for (int i = 0; i < 4; ++i)
            #pragma unroll
            for (int j = 0; j < NJ; ++j)
                acc[i][j] = __builtin_amdgcn_mfma_f32_16x16x32_bf16(
                    af[i], bfr[j], acc[i][j], 0, 0, 0);
    }

    #pragma unroll
    for (int i = 0; i < 4; ++i) {
        #pragma unroll
        for (int j = 0; j < NJ; ++j) {
            int row = row0 + wm + i * 16 + r_q * 4;
            int col = col0 + wn + j * 16 + r_m;
            if (col < N) {
                if (EPI == 1) {
                    float bv = bias[col];
                    #pragma unroll
                    for (int r = 0; r < 4; ++r)
                        Cb[(size_t)(row + r) * ldc + col] =
                            __float2bfloat16(softplus_f(acc[i][j][r] + bv));
                } else {
                    #pragma unroll
                    for (int r = 0; r < 4; ++r)
                        Cz[(size_t)(row + r) * ldc + col] = acc[i][j][r];
                }
            }
        }
    }
}

// reduce 8 split-K partials (ldc=256) -> x_dbl fp32 (160 cols) + dt_low bf16
__global__ __launch_bounds__(256)
void reduce_xdbl(const float* __restrict__ Cpart, float* __restrict__ x_dbl,
                 bf16* __restrict__ dtA_bf)
{
    int i = blockIdx.x * 256 + threadIdx.x;          // 2048*160
    if (i >= 2048 * XCOLS) return;
    int r = i / XCOLS, c = i - r * XCOLS;
    float s = 0.f;
    #pragma unroll
    for (int z = 0; z < 8; ++z)
        s += Cpart[(size_t)z * 2048 * 256 + (size_t)r * 256 + c];
    x_dbl[i] = s;
    if (c < DT_RANK) dtA_bf[(size_t)r * DT_RANK + c] = __float2bfloat16(s);
}

// reduce 2 split-K partials -> out fp32, float4
__global__ __launch_bounds__(256)
void reduce_out(const float* __restrict__ Cpart, float* __restrict__ out)
{
    int i = blockIdx.x * 256 + threadIdx.x;          // (2048*1024)/4
    const float4* p0 = (const float4*)Cpart;
    const float4* p1 = p0 + (size_t)2048 * 1024 / 4;
    float4 a = p0[i], b = p1[i];
    float4 r; r.x = a.x + b.x; r.y = a.y + b.y; r.z = a.z + b.z; r.w = a.w + b.w;
    ((float4*)out)[i] = r;
}

// ---------------- conv + silu (float4 over d), bf16 output only --------------
__global__ __launch_bounds__(256)
void conv_silu_kernel(const float* __restrict__ xz,
                      const float* __restrict__ conv_k,
                      const float* __restrict__ conv_b,
                      bf16* __restrict__ u_bf)
{
    int idx4 = blockIdx.x * 256 + threadIdx.x;       // B*L*Di/4 = 1048576
    int d4 = idx4 & (D_INNER / 4 - 1);
    int t = (idx4 >> 9) & (SEQLEN - 1);
    int b = idx4 >> 19;
    float4 acc = ((const float4*)conv_b)[d4];
    #pragma unroll
    for (int k = 0; k < D_CONV; ++k) {
        int tt = t + k - (D_CONV - 1);
        if (tt >= 0) {
            float4 xv = ((const float4*)xz)[(size_t)(b * SEQLEN + tt) * (2 * D_INNER / 4) + d4];
            float4 kv = ((const float4*)conv_k)[k * (D_INNER / 4) + d4];
            acc.x = fmaf(xv.x, kv.x, acc.x);
            acc.y = fmaf(xv.y, kv.y, acc.y);
            acc.z = fmaf(xv.z, kv.z, acc.z);
            acc.w = fmaf(xv.w, kv.w, acc.w);
        }
    }
    ushort4 pk;
    pk.x = f2bf_bits(acc.x / (1.f + __expf(-acc.x)));
    pk.y = f2bf_bits(acc.y / (1.f + __expf(-acc.y)));
    pk.z = f2bf_bits(acc.z / (1.f + __expf(-acc.z)));
    pk.w = f2bf_bits(acc.w / (1.f + __expf(-acc.w)));
    ((ushort4*)u_bf)[idx4] = pk;
}

// ---------------- chunked scan ----------------
// dt_sb = bf16 softplus(dt_pre + b_dt) (GEMM4 epilogue).
__global__ __launch_bounds__(256)
void scan_phase1(const bf16* __restrict__ dt_sb,
                 const float* __restrict__ Aneg,
                 const bf16* __restrict__ u_bf,
                 const float* __restrict__ x_dbl,
                 float* __restrict__ Pst, float* __restrict__ Sst)
{
    __shared__ float Bsm[LCHUNK][16];
    const int d = blockIdx.x * 256 + threadIdx.x;
    const int c = blockIdx.y, b = blockIdx.z;
    const int t0 = c * LCHUNK;
    {   // stage B rows (shared by all d in block)
        int tt = threadIdx.x >> 4, n = threadIdx.x & 15;
        Bsm[tt][n] = x_dbl[(size_t)(b * SEQLEN + t0 + tt) * XCOLS + DT_RANK + n];
    }
    float A_row[D_STATE];
    const float4* a4 = (const float4*)(Aneg + d * D_STATE);
    #pragma unroll
    for (int q = 0; q < 4; ++q) {
        float4 v = a4[q];
        A_row[q*4+0] = v.x; A_row[q*4+1] = v.y; A_row[q*4+2] = v.z; A_row[q*4+3] = v.w;
    }
    __syncthreads();
    float P[D_STATE], S[D_STATE];
    #pragma unroll
    for (int n = 0; n < D_STATE; ++n) { P[n] = 1.f; S[n] = 0.f; }
    const bf16* dpp = dt_sb + (size_t)(b * SEQLEN + t0) * D_INNER + d;
    const bf16* upp = u_bf + (size_t)(b * SEQLEN + t0) * D_INNER + d;
    #pragma unroll
    for (int t = 0; t < LCHUNK; ++t) {
        float dtv = __bfloat162float(dpp[(size_t)t * D_INNER]);
        float du = dtv * __bfloat162float(upp[(size_t)t * D_INNER]);
        const float4* b4 = (const float4*)&Bsm[t][0];
        #pragma unroll
        for (int q = 0; q < 4; ++q) {
            float4 v = b4[q];
            float Bn[4] = {v.x, v.y, v.z, v.w};
            #pragma unroll
            for (int e = 0; e < 4; ++e) {
                int n = q * 4 + e;
                float a = __expf(dtv * A_row[n]);
                P[n] *= a;
                S[n] = fmaf(a, S[n], du * Bn[e]);
            }
        }
    }
    const size_t base = ((size_t)(b * NCHUNK + c) * D_STATE) * D_INNER + d;
    #pragma unroll
    for (int n = 0; n < D_STATE; ++n) {
        Pst[base + (size_t)n * D_INNER] = P[n];
        Sst[base + (size_t)n * D_INNER] = S[n];
    }
}

// Phase 2: combine chunk transforms; write h_in per chunk IN-PLACE over Sst.
__global__ __launch_bounds__(256)
void scan_phase2(const float* __restrict__ Pst, float* __restrict__ Sst)
{
    const int d = blockIdx.x * 256 + threadIdx.x;
    const int n = blockIdx.y;
    const int b = blockIdx.z;
    float h = 0.f;
    for (int c = 0; c < NCHUNK; ++c) {
        const size_t idx = ((size_t)(b * NCHUNK + c) * D_STATE + n) * D_INNER + d;
        float Pv = Pst[idx], Sv = Sst[idx];
        Sst[idx] = h;                       // h_in for chunk c
        h = fmaf(Pv, h, Sv);
    }
}

__global__ __launch_bounds__(256)
void scan_phase3(const bf16* __restrict__ dt_sb,
                 const float* __restrict__ Aneg,
                 const bf16* __restrict__ u_bf,
                 const float* __restrict__ x_dbl,
                 const float* __restrict__ Dvec,
                 const float* __restrict__ xz,
                 const float* __restrict__ hin,   // == Sst after phase2
                 bf16* __restrict__ g_bf)
{
    __shared__ float BCs[LCHUNK][32];
    const int d = blockIdx.x * 256 + threadIdx.x;
    const int c = blockIdx.y, b = blockIdx.z;
    const int t0 = c * LCHUNK;
    {   // stage B and C rows
        int i0 = threadIdx.x;
        int tt = i0 >> 5, col = i0 & 31;
        BCs[tt][col] = x_dbl[(size_t)(b * SEQLEN + t0 + tt) * XCOLS + DT_RANK + col];
        int i1 = i0 + 256;
        tt = i1 >> 5; col = i1 & 31;
        BCs[tt][col] = x_dbl[(size_t)(b * SEQLEN + t0 + tt) * XCOLS + DT_RANK + col];
    }
    float A_row[D_STATE];
    const float4* a4 = (const float4*)(Aneg + d * D_STATE);
    #pragma unroll
    for (int q = 0; q < 4; ++q) {
        float4 v = a4[q];
        A_row[q*4+0] = v.x; A_row[q*4+1] = v.y; A_row[q*4+2] = v.z; A_row[q*4+3] = v.w;
    }
    const float Dd = Dvec[d];
    __syncthreads();
    float h[D_STATE];
    const size_t base = ((size_t)(b * NCHUNK + c) * D_STATE) * D_INNER + d;
    #pragma unroll
    for (int n = 0; n < D_STATE; ++n) h[n] = hin[base + (size_t)n * D_INNER];
    const bf16* dpp = dt_sb + (size_t)(b * SEQLEN + t0) * D_INNER + d;
    const bf16* upp = u_bf + (size_t)(b * SEQLEN + t0) * D_INNER + d;
    const float* zpp = xz + (size_t)(b * SEQLEN + t0) * (2 * D_INNER) + D_INNER + d;
    bf16* gpp = g_bf + (size_t)(b * SEQLEN + t0) * D_INNER + d;
    #pragma unroll
    for (int t = 0; t < LCHUNK; ++t) {
        float dtv = __bfloat162float(dpp[(size_t)t * D_INNER]);
        float uv = __bfloat162float(upp[(size_t)t * D_INNER]);
        float zv = zpp[(size_t)t * 2 * D_INNER];
        float du = dtv * uv;
        float y = 0.f;
        const float4* bc4 = (const float4*)&BCs[t][0];
        #pragma unroll
        for (int q = 0; q < 4; ++q) {
            float4 v = bc4[q];
            float4 w = bc4[q + 4];
            float Bn[4] = {v.x, v.y, v.z, v.w};
            float Cn[4] = {w.x, w.y, w.z, w.w};
            #pragma unroll
            for (int e = 0; e < 4; ++e) {
                int n = q * 4 + e;
                float a = __expf(dtv * A_row[n]);
                h[n] = fmaf(a, h[n], du * Bn[e]);
                y = fmaf(h[n], Cn[e], y);
            }
        }
        float gy = y + uv * Dd;
        float sz = zv / (1.f + __expf(-zv));
        gpp[(size_t)t * D_INNER] = __float2bfloat16(gy * sz);
    }
}

extern "C" void kernel_launch(void* const* d_in, const int* in_sizes, int n_in,
                              void* d_out, int out_size, void* d_ws, size_t ws_size,
                              hipStream_t stream)
{
    const float* x      = (const float*)d_in[0];
    const float* W_in   = (const float*)d_in[1];
    const float* conv_k = (const float*)d_in[2];
    const float* conv_b = (const float*)d_in[3];
    const float* W_xproj= (const float*)d_in[4];
    const float* W_dt   = (const float*)d_in[5];
    const float* b_dt   = (const float*)d_in[6];
    const float* A_log  = (const float*)d_in[7];
    const float* Dvec   = (const float*)d_in[8];
    const float* W_out  = (const float*)d_in[9];
    float* out = (float*)d_out;

    const int BL = BATCH * SEQLEN;                    // 2048

    // fp32 region
    float* ws     = (float*)d_ws;
    float* xz     = ws;                                 // 8,388,608
    float* x_dbl  = xz     + (size_t)BL * 2 * D_INNER;  //   327,680
    float* Pst    = x_dbl  + (size_t)BL * XCOLS;        // 4,194,304
    float* Sst    = Pst    + (size_t)BATCH * NCHUNK * D_STATE * D_INNER; // 4,194,304
    float* Aneg   = Sst    + (size_t)BATCH * NCHUNK * D_STATE * D_INNER; // 32,768
    float* Cpart3 = Pst;     // 8 x 2048 x 256 = 4,194,304 (Pst dead then)
    float* Cpart6 = Pst;     // 2 x 2048 x 1024 = 4,194,304 (Pst dead after phase2)
    bf16*  x_bf   = (bf16*)Sst;  // 2048x1024, dead before phase1
    // bf16 region
    bf16* Win_t  = (bf16*)(Aneg + 32768);               // 4096 x 1024
    bf16* u_bf   = Win_t + (size_t)4096 * 1024;         // 2048 x 2048
    bf16* Wxp_t  = u_bf  + (size_t)BL * D_INNER;        // 256  x 2048 (padded)
    bf16* dtA_bf = Wxp_t + (size_t)256 * 2048;          // 2048 x 128
    bf16* Wdt_t  = dtA_bf+ (size_t)BL * DT_RANK;        // 2048 x 128
    bf16* g_bf   = Wdt_t + (size_t)2048 * 128;          // 2048 x 2048
    bf16* Wout_t = g_bf  + (size_t)BL * D_INNER;        // 1024 x 2048
    bf16* dt_sb  = Wout_t+ (size_t)1024 * 2048;         // 2048 x 2048

    // 0) fused prep: 4 transposes + x convert + Aneg
    prep_kernel<<<4096 + 512 + 256 + 2048 + 2048 + 128, 256, 0, stream>>>(
        x, x_bf, W_in, Win_t, W_xproj, Wxp_t, W_dt, Wdt_t, W_out, Wout_t, A_log, Aneg);

    // 1) xz = x @ W_in            (2048x1024)@(1024x4096), 512 blocks
    gemm_mfma<128, 0><<<dim3(32, 16, 1), 256, 0, stream>>>(
        x_bf, Win_t, xz, nullptr, nullptr, BL, 2 * D_INNER, D_MODEL, 2 * D_INNER, D_MODEL);

    // 2) u_bf = bf16(silu(causal_conv(xz[:, :2048]) + b))
    conv_silu_kernel<<<(BL * D_INNER / 4) / 256, 256, 0, stream>>>(xz, conv_k, conv_b, u_bf);

    // 3) x_dbl = u @ W_xproj  split-K 8, BN=64 -> 512 blocks
    gemm_mfma<64, 0><<<dim3(4, 16, 8), 256, 0, stream>>>(
        u_bf, Wxp_t, Cpart3, nullptr, nullptr, BL, 256, D_INNER, 256, 256);
    reduce_xdbl<<<(BL * XCOLS + 255) / 256, 256, 0, stream>>>(Cpart3, x_dbl, dtA_bf);

    // 4) dt_sb = bf16(softplus(dt_low @ W_dt + b_dt)), BN=64 -> 512 blocks
    gemm_mfma<64, 1><<<dim3(32, 16, 1), 256, 0, stream>>>(
        dtA_bf, Wdt_t, nullptr, dt_sb, b_dt, BL, D_INNER, DT_RANK, D_INNER, DT_RANK);

    // 5) chunked selective scan -> g_bf = bf16((y + u*D) * silu(z))
    scan_phase1<<<dim3(D_INNER / 256, NCHUNK, BATCH), 256, 0, stream>>>(
        dt_sb, Aneg, u_bf, x_dbl, Pst, Sst);
    scan_phase2<<<dim3(D_INNER / 256, D_STATE, BATCH), 256, 0, stream>>>(Pst, Sst);
    scan_phase3<<<dim3(D_INNER / 256, NCHUNK, BATCH), 256, 0, stream>>>(
        dt_sb, Aneg, u_bf, x_dbl, Dvec, xz, Sst, g_bf);

    // 6) out = g @ W_out  split-K 2, BN=64 -> 512 blocks
    gemm_mfma<64, 0><<<dim3(16, 16, 2), 256, 0, stream>>>(
        g_bf, Wout_t, Cpart6, nullptr, nullptr, BL, D_MODEL, D_INNER, D_MODEL, D_MODEL);
    reduce_out<<<(BL * D_MODEL / 4) / 256, 256, 0, stream>>>(Cpart6, out);
}